// Round 1
// baseline (187.738 us; speedup 1.0000x reference)
//
#include <hip/hip_runtime.h>
#include <math.h>

#define EPSV 1e-12f

namespace {
constexpr int N_  = 4;
constexpr int C_  = 128;
constexpr int H_  = 30;
constexpr int W_  = 40;
constexpr int K_  = 64;
constexpr int HW_ = H_ * W_;        // 1200
constexpr int HP_ = 27;             // H+1-4
constexpr int WP_ = 37;             // W+1-4
constexpr int P_  = HP_ * WP_;      // 999
constexpr int KC_ = K_ * C_;        // 8192
}

// ---------------------------------------------------------------------------
// K1: per (n,h) row — L2-normalize x over channels, write xn in two layouts
//     (c-major xnT for the box-sum kernels, pixel-major xnP for vlad_global),
//     compute conv scores + softmax -> sa  (layout [n][k][pix])
// ---------------------------------------------------------------------------
__global__ __launch_bounds__(256) void k1_norm_softmax(
    const float* __restrict__ x, const float* __restrict__ conv_w,
    float* __restrict__ xnT, float* __restrict__ xnP, float* __restrict__ sa)
{
    __shared__ float xrow[C_ * W_];   // [c][w]
    __shared__ float conv_s[K_ * C_]; // [k][c]
    __shared__ float invn[W_];
    __shared__ float s_s[K_ * W_];    // [k][w]

    const int b = blockIdx.x;         // n*H + h
    const int n = b / H_, h = b - n * H_;
    const int t = threadIdx.x;

    for (int i = t; i < C_ * W_; i += 256) {
        const int c = i / W_, w = i - c * W_;
        xrow[i] = x[(size_t)(n * C_ + c) * HW_ + h * W_ + w];
    }
    for (int i = t; i < K_ * C_; i += 256) conv_s[i] = conv_w[i];
    __syncthreads();

    if (t < W_) {
        float s = 0.f;
        for (int c = 0; c < C_; ++c) { const float v = xrow[c * W_ + t]; s += v * v; }
        invn[t] = 1.f / fmaxf(sqrtf(s), EPSV);
    }
    __syncthreads();

    for (int i = t; i < C_ * W_; i += 256) {
        const int c = i / W_, w = i - c * W_;
        const float v = xrow[i] * invn[w];
        xrow[i] = v;
        xnT[(size_t)(n * C_ + c) * HW_ + h * W_ + w] = v;
    }
    __syncthreads();

    // pixel-major copy (coalesced: c fastest)
    for (int i = t; i < W_ * C_; i += 256) {
        const int w = i / C_, c = i - w * C_;
        xnP[((size_t)n * HW_ + h * W_ + w) * C_ + c] = xrow[c * W_ + w];
    }

    // scores
    for (int d = t; d < K_ * W_; d += 256) {
        const int k = d / W_, w = d - k * W_;
        const float* cw = &conv_s[k * C_];
        float s = 0.f;
        for (int c = 0; c < C_; ++c) s += cw[c] * xrow[c * W_ + w];
        s_s[d] = s;
    }
    __syncthreads();

    if (t < W_) {
        const int w = t;
        float m = -1e30f;
        for (int k = 0; k < K_; ++k) m = fmaxf(m, s_s[k * W_ + w]);
        float sum = 0.f;
        for (int k = 0; k < K_; ++k) sum += expf(s_s[k * W_ + w] - m);
        const float inv = 1.f / sum;
        for (int k = 0; k < K_; ++k)
            sa[(size_t)(n * K_ + k) * HW_ + h * W_ + w] = expf(s_s[k * W_ + w] - m) * inv;
    }
}

// ---------------------------------------------------------------------------
// K2: vlad_global per (n,k): G_c = sum_pix sa*xn ; vg = G - cent*sum(sa);
//     L2-normalize over c, store u and the norm-ratio r for the 2nd norm.
// ---------------------------------------------------------------------------
__global__ __launch_bounds__(128) void k2_vg(
    const float* __restrict__ sa, const float* __restrict__ xnP,
    const float* __restrict__ cent, float* __restrict__ vg_u,
    float* __restrict__ vg_r)
{
    const int b = blockIdx.x;         // n*K + k
    const int n = b >> 6, k = b & 63;
    const int c = threadIdx.x;

    const float* sarow = &sa[(size_t)b * HW_];
    const float* xp = &xnP[(size_t)n * HW_ * C_];
    float g = 0.f, bs = 0.f;
    for (int pix = 0; pix < HW_; ++pix) {
        const float s = sarow[pix];
        g += s * xp[(size_t)pix * C_ + c];
        bs += s;
    }
    const float vg = g - cent[k * C_ + c] * bs;

    float nsq = vg * vg;
    for (int off = 32; off >= 1; off >>= 1) nsq += __shfl_down(nsq, off);
    __shared__ float red[2];
    if ((threadIdx.x & 63) == 0) red[threadIdx.x >> 6] = nsq;
    __syncthreads();
    const float tot  = red[0] + red[1];
    const float norm = sqrtf(tot);
    const float iv   = 1.f / fmaxf(norm, EPSV);
    vg_u[(size_t)b * C_ + c] = vg * iv;
    if (c == 0) { const float rr = norm * iv; vg_r[b] = rr * rr; }
}

// K3: finalize vlad_global: second L2 norm across KC (per n), write output 0.
__global__ __launch_bounds__(256) void k3_vg_fin(
    const float* __restrict__ vg_u, const float* __restrict__ vg_r,
    float* __restrict__ out)
{
    const int n = blockIdx.x;
    const int t = threadIdx.x;
    __shared__ float inv2s;
    if (t == 0) {
        float s = 0.f;
        for (int k = 0; k < K_; ++k) s += vg_r[n * K_ + k];
        inv2s = 1.f / fmaxf(sqrtf(s), EPSV);
    }
    __syncthreads();
    const float inv2 = inv2s;
    for (int i = t; i < KC_; i += 256)
        out[(size_t)n * KC_ + i] = vg_u[(size_t)n * KC_ + i] * inv2;
}

// ---------------------------------------------------------------------------
// K4: local pass 1 — per (n,k,cq) block (32 channels, float4 x 8 groups),
//     compute box-sums via LDS column-sum + row-sum, accumulate sum of vl^2
//     per patch into registers; write partial normsq.
// ---------------------------------------------------------------------------
__global__ __launch_bounds__(256) void k4_local_norm(
    const float* __restrict__ sa, const float* __restrict__ xnT,
    const float* __restrict__ cent, float* __restrict__ nsqp)
{
    __shared__ float  sa_s[HW_];
    __shared__ float  B_s[P_];
    __shared__ float4 prod_s[HW_];
    __shared__ float4 cs_s[HP_ * W_];

    const int b  = blockIdx.x;            // ((n*K + k)*4 + cq)
    const int cq = b & 3;
    const int nk = b >> 2;
    const int n  = nk >> 6, k = nk & 63;
    const int t  = threadIdx.x;

    for (int i = t; i < HW_; i += 256) sa_s[i] = sa[(size_t)nk * HW_ + i];
    __syncthreads();
    for (int p = t; p < P_; p += 256) {
        const int hp = p / WP_, wp = p - hp * WP_;
        float bs = 0.f;
#pragma unroll
        for (int dh = 0; dh < 4; ++dh) {
            const float* r = &sa_s[(hp + dh) * W_ + wp];
            bs += r[0] + r[1] + r[2] + r[3];
        }
        B_s[p] = bs;
    }

    float nsq0 = 0.f, nsq1 = 0.f, nsq2 = 0.f, nsq3 = 0.f;
    const float* xb = xnT + (size_t)n * C_ * HW_;

    for (int g = 0; g < 8; ++g) {
        const int c0 = cq * 32 + g * 4;
        const float* x0 = xb + (size_t)(c0 + 0) * HW_;
        const float* x1 = xb + (size_t)(c0 + 1) * HW_;
        const float* x2 = xb + (size_t)(c0 + 2) * HW_;
        const float* x3 = xb + (size_t)(c0 + 3) * HW_;
        __syncthreads();   // prior iteration's cs_s readers done; B_s visible
        for (int i = t; i < HW_; i += 256) {
            const float s = sa_s[i];
            prod_s[i] = make_float4(s * x0[i], s * x1[i], s * x2[i], s * x3[i]);
        }
        __syncthreads();
        for (int i = t; i < HP_ * W_; i += 256) {
            const float4 a  = prod_s[i];
            const float4 b2 = prod_s[i + W_];
            const float4 c2 = prod_s[i + 2 * W_];
            const float4 d2 = prod_s[i + 3 * W_];
            cs_s[i] = make_float4(a.x + b2.x + c2.x + d2.x,
                                  a.y + b2.y + c2.y + d2.y,
                                  a.z + b2.z + c2.z + d2.z,
                                  a.w + b2.w + c2.w + d2.w);
        }
        __syncthreads();
        const float4 ce = *reinterpret_cast<const float4*>(&cent[k * C_ + c0]);
#pragma unroll
        for (int pi = 0; pi < 4; ++pi) {
            const int p = t + pi * 256;
            if (p < P_) {
                const int hp = p / WP_, wp = p - hp * WP_;
                const int base = hp * W_ + wp;
                const float4 s0 = cs_s[base], s1 = cs_s[base + 1],
                             s2 = cs_s[base + 2], s3 = cs_s[base + 3];
                const float Bv = B_s[p];
                const float ux = (s0.x + s1.x + s2.x + s3.x) - ce.x * Bv;
                const float uy = (s0.y + s1.y + s2.y + s3.y) - ce.y * Bv;
                const float uz = (s0.z + s1.z + s2.z + s3.z) - ce.z * Bv;
                const float uw = (s0.w + s1.w + s2.w + s3.w) - ce.w * Bv;
                const float add = ux * ux + uy * uy + uz * uz + uw * uw;
                if      (pi == 0) nsq0 += add;
                else if (pi == 1) nsq1 += add;
                else if (pi == 2) nsq2 += add;
                else              nsq3 += add;
            }
        }
    }
#pragma unroll
    for (int pi = 0; pi < 4; ++pi) {
        const int p = t + pi * 256;
        if (p < P_) {
            const float v = (pi == 0 ? nsq0 : pi == 1 ? nsq1 : pi == 2 ? nsq2 : nsq3);
            nsqp[(size_t)b * P_ + p] = v * 0.00390625f;  // (1/16)^2
        }
    }
}

// K5: combine 4 channel-quarter partials -> per (n,k,p) inv-norm + ratio.
__global__ __launch_bounds__(256) void k5_combine(
    const float* __restrict__ nsqp, float* __restrict__ inv1,
    float* __restrict__ rloc)
{
    const int nk = blockIdx.x;
    const int t  = threadIdx.x;
    for (int p = t; p < P_; p += 256) {
        const float s = nsqp[(size_t)(nk * 4 + 0) * P_ + p]
                      + nsqp[(size_t)(nk * 4 + 1) * P_ + p]
                      + nsqp[(size_t)(nk * 4 + 2) * P_ + p]
                      + nsqp[(size_t)(nk * 4 + 3) * P_ + p];
        const float norm = sqrtf(s);
        const float iv = 1.f / fmaxf(norm, EPSV);
        inv1[(size_t)nk * P_ + p] = iv;
        const float rr = norm * iv;
        rloc[(size_t)nk * P_ + p] = rr * rr;
    }
}

// K6: inv2[n,p] = 1/max(sqrt(sum_k r),EPS)
__global__ __launch_bounds__(256) void k6_inv2(
    const float* __restrict__ rloc, float* __restrict__ inv2)
{
    const int n = blockIdx.x >> 2;
    const int p = (blockIdx.x & 3) * 256 + threadIdx.x;
    if (p < P_) {
        float s = 0.f;
        for (int k = 0; k < K_; ++k) s += rloc[(size_t)(n * K_ + k) * P_ + p];
        inv2[n * P_ + p] = 1.f / fmaxf(sqrtf(s), EPSV);
    }
}

// ---------------------------------------------------------------------------
// K7: local pass 2 — recompute box-sums, scale by inv1*inv2/16, write output 1
//     rows (contiguous 999 floats per (n,k,c)) fully coalesced.
// ---------------------------------------------------------------------------
__global__ __launch_bounds__(256) void k7_local_write(
    const float* __restrict__ sa, const float* __restrict__ xnT,
    const float* __restrict__ cent, const float* __restrict__ inv1,
    const float* __restrict__ inv2, float* __restrict__ outl)
{
    __shared__ float  sa_s[HW_];
    __shared__ float  scl_s[P_];
    __shared__ float  t2_s[P_];
    __shared__ float4 prod_s[HW_];
    __shared__ float4 cs_s[HP_ * W_];

    const int b  = blockIdx.x;
    const int cq = b & 3;
    const int nk = b >> 2;
    const int n  = nk >> 6, k = nk & 63;
    const int t  = threadIdx.x;

    for (int i = t; i < HW_; i += 256) sa_s[i] = sa[(size_t)nk * HW_ + i];
    __syncthreads();
    for (int p = t; p < P_; p += 256) {
        const int hp = p / WP_, wp = p - hp * WP_;
        float bs = 0.f;
#pragma unroll
        for (int dh = 0; dh < 4; ++dh) {
            const float* r = &sa_s[(hp + dh) * W_ + wp];
            bs += r[0] + r[1] + r[2] + r[3];
        }
        const float scl = 0.0625f * inv1[(size_t)nk * P_ + p] * inv2[n * P_ + p];
        scl_s[p] = scl;
        t2_s[p]  = bs * scl;
    }

    const float* xb = xnT + (size_t)n * C_ * HW_;
    float* ob = outl + (size_t)nk * C_ * P_;

    for (int g = 0; g < 8; ++g) {
        const int c0 = cq * 32 + g * 4;
        const float* x0 = xb + (size_t)(c0 + 0) * HW_;
        const float* x1 = xb + (size_t)(c0 + 1) * HW_;
        const float* x2 = xb + (size_t)(c0 + 2) * HW_;
        const float* x3 = xb + (size_t)(c0 + 3) * HW_;
        __syncthreads();
        for (int i = t; i < HW_; i += 256) {
            const float s = sa_s[i];
            prod_s[i] = make_float4(s * x0[i], s * x1[i], s * x2[i], s * x3[i]);
        }
        __syncthreads();
        for (int i = t; i < HP_ * W_; i += 256) {
            const float4 a  = prod_s[i];
            const float4 b2 = prod_s[i + W_];
            const float4 c2 = prod_s[i + 2 * W_];
            const float4 d2 = prod_s[i + 3 * W_];
            cs_s[i] = make_float4(a.x + b2.x + c2.x + d2.x,
                                  a.y + b2.y + c2.y + d2.y,
                                  a.z + b2.z + c2.z + d2.z,
                                  a.w + b2.w + c2.w + d2.w);
        }
        __syncthreads();
        const float4 ce = *reinterpret_cast<const float4*>(&cent[k * C_ + c0]);
#pragma unroll
        for (int pi = 0; pi < 4; ++pi) {
            const int p = t + pi * 256;
            if (p < P_) {
                const int hp = p / WP_, wp = p - hp * WP_;
                const int base = hp * W_ + wp;
                const float4 s0 = cs_s[base], s1 = cs_s[base + 1],
                             s2 = cs_s[base + 2], s3 = cs_s[base + 3];
                const float scl = scl_s[p];
                const float tt  = t2_s[p];
                ob[(size_t)(c0 + 0) * P_ + p] = (s0.x + s1.x + s2.x + s3.x) * scl - ce.x * tt;
                ob[(size_t)(c0 + 1) * P_ + p] = (s0.y + s1.y + s2.y + s3.y) * scl - ce.y * tt;
                ob[(size_t)(c0 + 2) * P_ + p] = (s0.z + s1.z + s2.z + s3.z) * scl - ce.z * tt;
                ob[(size_t)(c0 + 3) * P_ + p] = (s0.w + s1.w + s2.w + s3.w) * scl - ce.w * tt;
            }
        }
    }
}

// ---------------------------------------------------------------------------
extern "C" void kernel_launch(void* const* d_in, const int* in_sizes, int n_in,
                              void* d_out, int out_size, void* d_ws, size_t ws_size,
                              hipStream_t stream)
{
    const float* x      = (const float*)d_in[0];
    const float* conv_w = (const float*)d_in[1];
    const float* cent   = (const float*)d_in[2];
    float* out = (float*)d_out;
    float* ws  = (float*)d_ws;

    // workspace layout (floats)
    float* xnT  = ws;                       // 614400
    float* xnP  = ws + 614400;              // 614400
    float* sa   = ws + 1228800;             // 307200
    float* vg_u = ws + 1536000;             // 32768
    float* vg_r = ws + 1568768;             // 256
    float* nsqp = ws + 1569024;             // 1022976
    float* inv1 = ws + 2592000;             // 255744
    float* rloc = ws + 2847744;             // 255744
    float* inv2 = ws + 3103488;             // 3996   (total ~12.4 MB)

    k1_norm_softmax<<<N_ * H_, 256, 0, stream>>>(x, conv_w, xnT, xnP, sa);
    k2_vg<<<N_ * K_, 128, 0, stream>>>(sa, xnP, cent, vg_u, vg_r);
    k3_vg_fin<<<N_, 256, 0, stream>>>(vg_u, vg_r, out);
    k4_local_norm<<<N_ * K_ * 4, 256, 0, stream>>>(sa, xnT, cent, nsqp);
    k5_combine<<<N_ * K_, 256, 0, stream>>>(nsqp, inv1, rloc);
    k6_inv2<<<N_ * 4, 256, 0, stream>>>(rloc, inv2);
    k7_local_write<<<N_ * K_ * 4, 256, 0, stream>>>(sa, xnT, cent, inv1, inv2,
                                                    out + (size_t)N_ * KC_);
}

// Round 2
// 146.726 us; speedup vs baseline: 1.2795x; 1.2795x over previous
//
#include <hip/hip_runtime.h>
#include <math.h>

#define EPSV 1e-12f

namespace {
constexpr int N_  = 4;
constexpr int C_  = 128;
constexpr int H_  = 30;
constexpr int W_  = 40;
constexpr int K_  = 64;
constexpr int HW_ = H_ * W_;        // 1200
constexpr int HP_ = 27;             // H+1-4
constexpr int WP_ = 37;             // W+1-4
constexpr int P_  = HP_ * WP_;      // 999
constexpr int KC_ = K_ * C_;        // 8192
constexpr int CP_ = C_ * P_;        // 127872 floats per (n,k) slab
constexpr int Q4_ = CP_ / 4 / 4;    // 7992 float4 per slab-quarter
}

// ---------------------------------------------------------------------------
// K1: per (n,h) row — L2-normalize x over channels, write xn in two layouts,
//     compute conv scores + softmax -> sa  (layout [n][k][pix])
// ---------------------------------------------------------------------------
__global__ __launch_bounds__(256) void k1_norm_softmax(
    const float* __restrict__ x, const float* __restrict__ conv_w,
    float* __restrict__ xnT, float* __restrict__ xnP, float* __restrict__ sa)
{
    __shared__ float xrow[C_ * W_];   // [c][w]
    __shared__ float conv_s[K_ * C_]; // [k][c]
    __shared__ float invn[W_];
    __shared__ float s_s[K_ * W_];    // [k][w]

    const int b = blockIdx.x;         // n*H + h
    const int n = b / H_, h = b - n * H_;
    const int t = threadIdx.x;

    for (int i = t; i < C_ * W_; i += 256) {
        const int c = i / W_, w = i - c * W_;
        xrow[i] = x[(size_t)(n * C_ + c) * HW_ + h * W_ + w];
    }
    for (int i = t; i < K_ * C_; i += 256) conv_s[i] = conv_w[i];
    __syncthreads();

    if (t < W_) {
        float s = 0.f;
        for (int c = 0; c < C_; ++c) { const float v = xrow[c * W_ + t]; s += v * v; }
        invn[t] = 1.f / fmaxf(sqrtf(s), EPSV);
    }
    __syncthreads();

    for (int i = t; i < C_ * W_; i += 256) {
        const int c = i / W_, w = i - c * W_;
        const float v = xrow[i] * invn[w];
        xrow[i] = v;
        xnT[(size_t)(n * C_ + c) * HW_ + h * W_ + w] = v;
    }
    __syncthreads();

    for (int i = t; i < W_ * C_; i += 256) {
        const int w = i / C_, c = i - w * C_;
        xnP[((size_t)n * HW_ + h * W_ + w) * C_ + c] = xrow[c * W_ + w];
    }

    for (int d = t; d < K_ * W_; d += 256) {
        const int k = d / W_, w = d - k * W_;
        const float* cw = &conv_s[k * C_];
        float s = 0.f;
        for (int c = 0; c < C_; ++c) s += cw[c] * xrow[c * W_ + w];
        s_s[d] = s;
    }
    __syncthreads();

    if (t < W_) {
        const int w = t;
        float m = -1e30f;
        for (int k = 0; k < K_; ++k) m = fmaxf(m, s_s[k * W_ + w]);
        float sum = 0.f;
        for (int k = 0; k < K_; ++k) sum += expf(s_s[k * W_ + w] - m);
        const float inv = 1.f / sum;
        for (int k = 0; k < K_; ++k)
            sa[(size_t)(n * K_ + k) * HW_ + h * W_ + w] = expf(s_s[k * W_ + w] - m) * inv;
    }
}

// ---------------------------------------------------------------------------
// K2: vlad_global per (n,k) — 4 independent accumulators to break the
//     serial FMA dependence chain.
// ---------------------------------------------------------------------------
__global__ __launch_bounds__(128) void k2_vg(
    const float* __restrict__ sa, const float* __restrict__ xnP,
    const float* __restrict__ cent, float* __restrict__ vg_u,
    float* __restrict__ vg_r)
{
    const int b = blockIdx.x;         // n*K + k
    const int n = b >> 6, k = b & 63;
    const int c = threadIdx.x;

    const float* sarow = &sa[(size_t)b * HW_];
    const float* xp = &xnP[(size_t)n * HW_ * C_ + c];
    float g0 = 0.f, g1 = 0.f, g2 = 0.f, g3 = 0.f;
    float b0 = 0.f, b1 = 0.f, b2 = 0.f, b3 = 0.f;
    for (int pix = 0; pix < HW_; pix += 4) {
        const float s0 = sarow[pix + 0], s1 = sarow[pix + 1];
        const float s2 = sarow[pix + 2], s3 = sarow[pix + 3];
        g0 += s0 * xp[(size_t)(pix + 0) * C_];
        g1 += s1 * xp[(size_t)(pix + 1) * C_];
        g2 += s2 * xp[(size_t)(pix + 2) * C_];
        g3 += s3 * xp[(size_t)(pix + 3) * C_];
        b0 += s0; b1 += s1; b2 += s2; b3 += s3;
    }
    const float g  = (g0 + g1) + (g2 + g3);
    const float bs = (b0 + b1) + (b2 + b3);
    const float vg = g - cent[k * C_ + c] * bs;

    float nsq = vg * vg;
    for (int off = 32; off >= 1; off >>= 1) nsq += __shfl_down(nsq, off);
    __shared__ float red[2];
    if ((threadIdx.x & 63) == 0) red[threadIdx.x >> 6] = nsq;
    __syncthreads();
    const float tot  = red[0] + red[1];
    const float norm = sqrtf(tot);
    const float iv   = 1.f / fmaxf(norm, EPSV);
    vg_u[(size_t)b * C_ + c] = vg * iv;
    if (c == 0) { const float rr = norm * iv; vg_r[b] = rr * rr; }
}

// K3: finalize vlad_global
__global__ __launch_bounds__(256) void k3_vg_fin(
    const float* __restrict__ vg_u, const float* __restrict__ vg_r,
    float* __restrict__ out)
{
    const int n = blockIdx.x;
    const int t = threadIdx.x;
    __shared__ float inv2s;
    if (t == 0) {
        float s = 0.f;
        for (int k = 0; k < K_; ++k) s += vg_r[n * K_ + k];
        inv2s = 1.f / fmaxf(sqrtf(s), EPSV);
    }
    __syncthreads();
    const float inv2 = inv2s;
    for (int i = t; i < KC_; i += 256)
        out[(size_t)n * KC_ + i] = vg_u[(size_t)n * KC_ + i] * inv2;
}

// ---------------------------------------------------------------------------
// K4: SINGLE box-sum pass. Fused product+column-sum (x read straight from
//     L2, no prod staging -> 2 barriers/group, 26 KB LDS, 6 blocks/CU).
//     Writes unnormalized vl/16 into the output buffer AND the per-cq
//     channel-norm partials.
// ---------------------------------------------------------------------------
__global__ __launch_bounds__(256) void k4_local(
    const float* __restrict__ sa, const float* __restrict__ xnT,
    const float* __restrict__ cent, float* __restrict__ nsqp,
    float* __restrict__ outl)
{
    __shared__ float  sa_s[HW_];
    __shared__ float  B_s[P_];
    __shared__ float4 cs_s[HP_ * W_];

    const int b  = blockIdx.x;            // ((n*K + k)*4 + cq)
    const int cq = b & 3;
    const int nk = b >> 2;
    const int n  = nk >> 6, k = nk & 63;
    const int t  = threadIdx.x;

    for (int i = t; i < HW_; i += 256) sa_s[i] = sa[(size_t)nk * HW_ + i];
    __syncthreads();
    for (int p = t; p < P_; p += 256) {
        const int hp = p / WP_, wp = p - hp * WP_;
        float bs = 0.f;
#pragma unroll
        for (int dh = 0; dh < 4; ++dh) {
            const float* r = &sa_s[(hp + dh) * W_ + wp];
            bs += r[0] + r[1] + r[2] + r[3];
        }
        B_s[p] = bs;
    }

    float nsq0 = 0.f, nsq1 = 0.f, nsq2 = 0.f, nsq3 = 0.f;
    const float* xb = xnT + (size_t)n * C_ * HW_;
    float* ob = outl + (size_t)nk * CP_;

    for (int g = 0; g < 8; ++g) {
        const int c0 = cq * 32 + g * 4;
        const float* x0 = xb + (size_t)(c0 + 0) * HW_;
        const float* x1 = xb + (size_t)(c0 + 1) * HW_;
        const float* x2 = xb + (size_t)(c0 + 2) * HW_;
        const float* x3 = xb + (size_t)(c0 + 3) * HW_;
        __syncthreads();   // prior group's cs_s readers done; B_s visible (g=0)
        for (int i = t; i < HP_ * W_; i += 256) {
            const float s0 = sa_s[i];
            const float s1 = sa_s[i + W_];
            const float s2 = sa_s[i + 2 * W_];
            const float s3 = sa_s[i + 3 * W_];
            cs_s[i] = make_float4(
                s0 * x0[i] + s1 * x0[i + W_] + s2 * x0[i + 2 * W_] + s3 * x0[i + 3 * W_],
                s0 * x1[i] + s1 * x1[i + W_] + s2 * x1[i + 2 * W_] + s3 * x1[i + 3 * W_],
                s0 * x2[i] + s1 * x2[i + W_] + s2 * x2[i + 2 * W_] + s3 * x2[i + 3 * W_],
                s0 * x3[i] + s1 * x3[i + W_] + s2 * x3[i + 2 * W_] + s3 * x3[i + 3 * W_]);
        }
        __syncthreads();
        const float4 ce = *reinterpret_cast<const float4*>(&cent[k * C_ + c0]);
#pragma unroll
        for (int pi = 0; pi < 4; ++pi) {
            const int p = t + pi * 256;
            if (p < P_) {
                const int hp = p / WP_, wp = p - hp * WP_;
                const int base = hp * W_ + wp;
                const float4 s0 = cs_s[base], s1 = cs_s[base + 1],
                             s2 = cs_s[base + 2], s3 = cs_s[base + 3];
                const float Bv = B_s[p];
                const float ux = (s0.x + s1.x + s2.x + s3.x) - ce.x * Bv;
                const float uy = (s0.y + s1.y + s2.y + s3.y) - ce.y * Bv;
                const float uz = (s0.z + s1.z + s2.z + s3.z) - ce.z * Bv;
                const float uw = (s0.w + s1.w + s2.w + s3.w) - ce.w * Bv;
                const float add = ux * ux + uy * uy + uz * uz + uw * uw;
                if      (pi == 0) nsq0 += add;
                else if (pi == 1) nsq1 += add;
                else if (pi == 2) nsq2 += add;
                else              nsq3 += add;
                ob[(size_t)(c0 + 0) * P_ + p] = ux * 0.0625f;
                ob[(size_t)(c0 + 1) * P_ + p] = uy * 0.0625f;
                ob[(size_t)(c0 + 2) * P_ + p] = uz * 0.0625f;
                ob[(size_t)(c0 + 3) * P_ + p] = uw * 0.0625f;
            }
        }
    }
#pragma unroll
    for (int pi = 0; pi < 4; ++pi) {
        const int p = t + pi * 256;
        if (p < P_) {
            const float v = (pi == 0 ? nsq0 : pi == 1 ? nsq1 : pi == 2 ? nsq2 : nsq3);
            nsqp[(size_t)b * P_ + p] = v * 0.00390625f;  // (1/16)^2
        }
    }
}

// K5: combine 4 channel-quarter partials -> per (n,k,p) inv-norm + ratio.
__global__ __launch_bounds__(256) void k5_combine(
    const float* __restrict__ nsqp, float* __restrict__ inv1,
    float* __restrict__ rloc)
{
    const int nk = blockIdx.x;
    const int t  = threadIdx.x;
    for (int p = t; p < P_; p += 256) {
        const float s = nsqp[(size_t)(nk * 4 + 0) * P_ + p]
                      + nsqp[(size_t)(nk * 4 + 1) * P_ + p]
                      + nsqp[(size_t)(nk * 4 + 2) * P_ + p]
                      + nsqp[(size_t)(nk * 4 + 3) * P_ + p];
        const float norm = sqrtf(s);
        const float iv = 1.f / fmaxf(norm, EPSV);
        inv1[(size_t)nk * P_ + p] = iv;
        const float rr = norm * iv;
        rloc[(size_t)nk * P_ + p] = rr * rr;
    }
}

// K6: inv2[n,p] = 1/max(sqrt(sum_k r),EPS)
__global__ __launch_bounds__(256) void k6_inv2(
    const float* __restrict__ rloc, float* __restrict__ inv2)
{
    const int n = blockIdx.x >> 2;
    const int p = (blockIdx.x & 3) * 256 + threadIdx.x;
    if (p < P_) {
        float s = 0.f;
        for (int k = 0; k < K_; ++k) s += rloc[(size_t)(n * K_ + k) * P_ + p];
        inv2[n * P_ + p] = 1.f / fmaxf(sqrtf(s), EPSV);
    }
}

// ---------------------------------------------------------------------------
// K8: in-place streaming scale of output1: out *= inv1[nk,p]*inv2[n,p].
//     float4 loads/stores; scl row cached in LDS per block.
// ---------------------------------------------------------------------------
__global__ __launch_bounds__(256) void k8_scale(
    float* __restrict__ outl, const float* __restrict__ inv1,
    const float* __restrict__ inv2)
{
    __shared__ float scl[P_];
    const int b  = blockIdx.x;       // nk*4 + q
    const int nk = b >> 2, q = b & 3;
    const int n  = nk >> 6;
    const int t  = threadIdx.x;

    for (int p = t; p < P_; p += 256)
        scl[p] = inv1[(size_t)nk * P_ + p] * inv2[n * P_ + p];
    __syncthreads();

    float4* base = reinterpret_cast<float4*>(outl + (size_t)nk * CP_);
    const int q0 = q * Q4_;
    for (int j = t; j < Q4_; j += 256) {
        const int f4 = q0 + j;
        const int f  = f4 * 4;
        float4 v = base[f4];
        int p = f - (f / P_) * P_;
        v.x *= scl[p]; if (++p == P_) p = 0;
        v.y *= scl[p]; if (++p == P_) p = 0;
        v.z *= scl[p]; if (++p == P_) p = 0;
        v.w *= scl[p];
        base[f4] = v;
    }
}

// ---------------------------------------------------------------------------
extern "C" void kernel_launch(void* const* d_in, const int* in_sizes, int n_in,
                              void* d_out, int out_size, void* d_ws, size_t ws_size,
                              hipStream_t stream)
{
    const float* x      = (const float*)d_in[0];
    const float* conv_w = (const float*)d_in[1];
    const float* cent   = (const float*)d_in[2];
    float* out = (float*)d_out;
    float* ws  = (float*)d_ws;

    // workspace layout (floats)
    float* xnT  = ws;                       // 614400
    float* xnP  = ws + 614400;              // 614400
    float* sa   = ws + 1228800;             // 307200
    float* vg_u = ws + 1536000;             // 32768
    float* vg_r = ws + 1568768;             // 256
    float* nsqp = ws + 1569024;             // 1022976
    float* inv1 = ws + 2592000;             // 255744
    float* rloc = ws + 2847744;             // 255744
    float* inv2 = ws + 3103488;             // 3996

    float* outl = out + (size_t)N_ * KC_;   // output 1 region

    k1_norm_softmax<<<N_ * H_, 256, 0, stream>>>(x, conv_w, xnT, xnP, sa);
    k2_vg<<<N_ * K_, 128, 0, stream>>>(sa, xnP, cent, vg_u, vg_r);
    k3_vg_fin<<<N_, 256, 0, stream>>>(vg_u, vg_r, out);
    k4_local<<<N_ * K_ * 4, 256, 0, stream>>>(sa, xnT, cent, nsqp, outl);
    k5_combine<<<N_ * K_, 256, 0, stream>>>(nsqp, inv1, rloc);
    k6_inv2<<<N_ * 4, 256, 0, stream>>>(rloc, inv2);
    k8_scale<<<N_ * K_ * 4, 256, 0, stream>>>(outl, inv1, inv2);
}

// Round 3
// 136.382 us; speedup vs baseline: 1.3766x; 1.0758x over previous
//
#include <hip/hip_runtime.h>
#include <math.h>

#define EPSV 1e-12f

namespace {
constexpr int N_  = 4;
constexpr int C_  = 128;
constexpr int H_  = 30;
constexpr int W_  = 40;
constexpr int K_  = 64;
constexpr int HW_ = H_ * W_;        // 1200
constexpr int HP_ = 27;             // H+1-4
constexpr int WP_ = 37;             // W+1-4
constexpr int P_  = HP_ * WP_;      // 999
constexpr int KC_ = K_ * C_;        // 8192
constexpr int CP_ = C_ * P_;        // 127872 floats per (n,k) slab
}

// ---------------------------------------------------------------------------
// K1: per (n,h) row — L2-normalize x over channels, write xn in two layouts,
//     compute conv scores + softmax -> sa  (layout [n][k][pix])
// ---------------------------------------------------------------------------
__global__ __launch_bounds__(256) void k1_norm_softmax(
    const float* __restrict__ x, const float* __restrict__ conv_w,
    float* __restrict__ xnT, float* __restrict__ xnP, float* __restrict__ sa)
{
    __shared__ float xrow[C_ * W_];   // [c][w]
    __shared__ float conv_s[K_ * C_]; // [k][c]
    __shared__ float invn[W_];
    __shared__ float s_s[K_ * W_];    // [k][w]

    const int b = blockIdx.x;         // n*H + h
    const int n = b / H_, h = b - n * H_;
    const int t = threadIdx.x;

    for (int i = t; i < C_ * W_; i += 256) {
        const int c = i / W_, w = i - c * W_;
        xrow[i] = x[(size_t)(n * C_ + c) * HW_ + h * W_ + w];
    }
    for (int i = t; i < K_ * C_; i += 256) conv_s[i] = conv_w[i];
    __syncthreads();

    if (t < W_) {
        float s = 0.f;
        for (int c = 0; c < C_; ++c) { const float v = xrow[c * W_ + t]; s += v * v; }
        invn[t] = 1.f / fmaxf(sqrtf(s), EPSV);
    }
    __syncthreads();

    for (int i = t; i < C_ * W_; i += 256) {
        const int c = i / W_, w = i - c * W_;
        const float v = xrow[i] * invn[w];
        xrow[i] = v;
        xnT[(size_t)(n * C_ + c) * HW_ + h * W_ + w] = v;
    }
    __syncthreads();

    for (int i = t; i < W_ * C_; i += 256) {
        const int w = i / C_, c = i - w * C_;
        xnP[((size_t)n * HW_ + h * W_ + w) * C_ + c] = xrow[c * W_ + w];
    }

    for (int d = t; d < K_ * W_; d += 256) {
        const int k = d / W_, w = d - k * W_;
        const float* cw = &conv_s[k * C_];
        float s = 0.f;
        for (int c = 0; c < C_; ++c) s += cw[c] * xrow[c * W_ + w];
        s_s[d] = s;
    }
    __syncthreads();

    if (t < W_) {
        const int w = t;
        float m = -1e30f;
        for (int k = 0; k < K_; ++k) m = fmaxf(m, s_s[k * W_ + w]);
        float sum = 0.f;
        for (int k = 0; k < K_; ++k) sum += expf(s_s[k * W_ + w] - m);
        const float inv = 1.f / sum;
        for (int k = 0; k < K_; ++k)
            sa[(size_t)(n * K_ + k) * HW_ + h * W_ + w] = expf(s_s[k * W_ + w] - m) * inv;
    }
}

// ---------------------------------------------------------------------------
// K2: vlad_global per (n,k) — 4 independent accumulators.
// ---------------------------------------------------------------------------
__global__ __launch_bounds__(128) void k2_vg(
    const float* __restrict__ sa, const float* __restrict__ xnP,
    const float* __restrict__ cent, float* __restrict__ vg_u,
    float* __restrict__ vg_r)
{
    const int b = blockIdx.x;         // n*K + k
    const int n = b >> 6, k = b & 63;
    const int c = threadIdx.x;

    const float* sarow = &sa[(size_t)b * HW_];
    const float* xp = &xnP[(size_t)n * HW_ * C_ + c];
    float g0 = 0.f, g1 = 0.f, g2 = 0.f, g3 = 0.f;
    float b0 = 0.f, b1 = 0.f, b2 = 0.f, b3 = 0.f;
    for (int pix = 0; pix < HW_; pix += 4) {
        const float s0 = sarow[pix + 0], s1 = sarow[pix + 1];
        const float s2 = sarow[pix + 2], s3 = sarow[pix + 3];
        g0 += s0 * xp[(size_t)(pix + 0) * C_];
        g1 += s1 * xp[(size_t)(pix + 1) * C_];
        g2 += s2 * xp[(size_t)(pix + 2) * C_];
        g3 += s3 * xp[(size_t)(pix + 3) * C_];
        b0 += s0; b1 += s1; b2 += s2; b3 += s3;
    }
    const float g  = (g0 + g1) + (g2 + g3);
    const float bs = (b0 + b1) + (b2 + b3);
    const float vg = g - cent[k * C_ + c] * bs;

    float nsq = vg * vg;
    for (int off = 32; off >= 1; off >>= 1) nsq += __shfl_down(nsq, off);
    __shared__ float red[2];
    if ((threadIdx.x & 63) == 0) red[threadIdx.x >> 6] = nsq;
    __syncthreads();
    const float tot  = red[0] + red[1];
    const float norm = sqrtf(tot);
    const float iv   = 1.f / fmaxf(norm, EPSV);
    vg_u[(size_t)b * C_ + c] = vg * iv;
    if (c == 0) { const float rr = norm * iv; vg_r[b] = rr * rr; }
}

// K3: finalize vlad_global
__global__ __launch_bounds__(256) void k3_vg_fin(
    const float* __restrict__ vg_u, const float* __restrict__ vg_r,
    float* __restrict__ out)
{
    const int n = blockIdx.x;
    const int t = threadIdx.x;
    __shared__ float inv2s;
    if (t == 0) {
        float s = 0.f;
        for (int k = 0; k < K_; ++k) s += vg_r[n * K_ + k];
        inv2s = 1.f / fmaxf(sqrtf(s), EPSV);
    }
    __syncthreads();
    const float inv2 = inv2s;
    for (int i = t; i < KC_; i += 256)
        out[(size_t)n * KC_ + i] = vg_u[(size_t)n * KC_ + i] * inv2;
}

// ---------------------------------------------------------------------------
// K4n: NORM-ONLY box-sum pass — fused product+column-sum, accumulates per-p
//      channel-norm partials; writes only nsqp (4 MB), NO output store.
// ---------------------------------------------------------------------------
__global__ __launch_bounds__(256) void k4_norm(
    const float* __restrict__ sa, const float* __restrict__ xnT,
    const float* __restrict__ cent, float* __restrict__ nsqp)
{
    __shared__ float  sa_s[HW_];
    __shared__ float  B_s[P_];
    __shared__ float4 cs_s[HP_ * W_];

    const int b  = blockIdx.x;            // ((n*K + k)*4 + cq)
    const int cq = b & 3;
    const int nk = b >> 2;
    const int n  = nk >> 6, k = nk & 63;
    const int t  = threadIdx.x;

    for (int i = t; i < HW_; i += 256) sa_s[i] = sa[(size_t)nk * HW_ + i];
    __syncthreads();
    for (int p = t; p < P_; p += 256) {
        const int hp = p / WP_, wp = p - hp * WP_;
        float bs = 0.f;
#pragma unroll
        for (int dh = 0; dh < 4; ++dh) {
            const float* r = &sa_s[(hp + dh) * W_ + wp];
            bs += r[0] + r[1] + r[2] + r[3];
        }
        B_s[p] = bs;
    }

    float nsq0 = 0.f, nsq1 = 0.f, nsq2 = 0.f, nsq3 = 0.f;
    const float* xb = xnT + (size_t)n * C_ * HW_;

    for (int g = 0; g < 8; ++g) {
        const int c0 = cq * 32 + g * 4;
        const float* x0 = xb + (size_t)(c0 + 0) * HW_;
        const float* x1 = xb + (size_t)(c0 + 1) * HW_;
        const float* x2 = xb + (size_t)(c0 + 2) * HW_;
        const float* x3 = xb + (size_t)(c0 + 3) * HW_;
        __syncthreads();   // prior group's cs_s readers done; B_s visible (g=0)
        for (int i = t; i < HP_ * W_; i += 256) {
            const float s0 = sa_s[i];
            const float s1 = sa_s[i + W_];
            const float s2 = sa_s[i + 2 * W_];
            const float s3 = sa_s[i + 3 * W_];
            cs_s[i] = make_float4(
                s0 * x0[i] + s1 * x0[i + W_] + s2 * x0[i + 2 * W_] + s3 * x0[i + 3 * W_],
                s0 * x1[i] + s1 * x1[i + W_] + s2 * x1[i + 2 * W_] + s3 * x1[i + 3 * W_],
                s0 * x2[i] + s1 * x2[i + W_] + s2 * x2[i + 2 * W_] + s3 * x2[i + 3 * W_],
                s0 * x3[i] + s1 * x3[i + W_] + s2 * x3[i + 2 * W_] + s3 * x3[i + 3 * W_]);
        }
        __syncthreads();
        const float4 ce = *reinterpret_cast<const float4*>(&cent[k * C_ + c0]);
#pragma unroll
        for (int pi = 0; pi < 4; ++pi) {
            const int p = t + pi * 256;
            if (p < P_) {
                const int hp = p / WP_, wp = p - hp * WP_;
                const int base = hp * W_ + wp;
                const float4 s0 = cs_s[base], s1 = cs_s[base + 1],
                             s2 = cs_s[base + 2], s3 = cs_s[base + 3];
                const float Bv = B_s[p];
                const float ux = (s0.x + s1.x + s2.x + s3.x) - ce.x * Bv;
                const float uy = (s0.y + s1.y + s2.y + s3.y) - ce.y * Bv;
                const float uz = (s0.z + s1.z + s2.z + s3.z) - ce.z * Bv;
                const float uw = (s0.w + s1.w + s2.w + s3.w) - ce.w * Bv;
                const float add = ux * ux + uy * uy + uz * uz + uw * uw;
                if      (pi == 0) nsq0 += add;
                else if (pi == 1) nsq1 += add;
                else if (pi == 2) nsq2 += add;
                else              nsq3 += add;
            }
        }
    }
#pragma unroll
    for (int pi = 0; pi < 4; ++pi) {
        const int p = t + pi * 256;
        if (p < P_) {
            const float v = (pi == 0 ? nsq0 : pi == 1 ? nsq1 : pi == 2 ? nsq2 : nsq3);
            nsqp[(size_t)b * P_ + p] = v * 0.00390625f;  // (1/16)^2
        }
    }
}

// K5: combine 4 channel-quarter partials -> per (n,k,p) scaled inv-norm
//     (0.0625 folded in) + ratio for the second norm.
__global__ __launch_bounds__(256) void k5_combine(
    const float* __restrict__ nsqp, float* __restrict__ inv1,
    float* __restrict__ rloc)
{
    const int nk = blockIdx.x;
    const int t  = threadIdx.x;
    for (int p = t; p < P_; p += 256) {
        const float s = nsqp[(size_t)(nk * 4 + 0) * P_ + p]
                      + nsqp[(size_t)(nk * 4 + 1) * P_ + p]
                      + nsqp[(size_t)(nk * 4 + 2) * P_ + p]
                      + nsqp[(size_t)(nk * 4 + 3) * P_ + p];
        const float norm = sqrtf(s);
        const float iv = 1.f / fmaxf(norm, EPSV);
        inv1[(size_t)nk * P_ + p] = iv * 0.0625f;   // fold 1/16
        const float rr = norm * iv;
        rloc[(size_t)nk * P_ + p] = rr * rr;
    }
}

// K6: inv2[n,p] = 1/max(sqrt(sum_k r),EPS)
__global__ __launch_bounds__(256) void k6_inv2(
    const float* __restrict__ rloc, float* __restrict__ inv2)
{
    const int n = blockIdx.x >> 2;
    const int p = (blockIdx.x & 3) * 256 + threadIdx.x;
    if (p < P_) {
        float s = 0.f;
        for (int k = 0; k < K_; ++k) s += rloc[(size_t)(n * K_ + k) * P_ + p];
        inv2[n * P_ + p] = 1.f / fmaxf(sqrtf(s), EPSV);
    }
}

// ---------------------------------------------------------------------------
// K7w: WRITE pass — recompute fused box-sums, apply scl = inv1*inv2 on the
//      fly, write output1 exactly once (fully coalesced rows).
// ---------------------------------------------------------------------------
__global__ __launch_bounds__(256) void k7_write(
    const float* __restrict__ sa, const float* __restrict__ xnT,
    const float* __restrict__ cent, const float* __restrict__ inv1,
    const float* __restrict__ inv2, float* __restrict__ outl)
{
    __shared__ float  sa_s[HW_];
    __shared__ float  scl_s[P_];
    __shared__ float  t2_s[P_];
    __shared__ float4 cs_s[HP_ * W_];

    const int b  = blockIdx.x;            // ((n*K + k)*4 + cq)
    const int cq = b & 3;
    const int nk = b >> 2;
    const int n  = nk >> 6, k = nk & 63;
    const int t  = threadIdx.x;

    for (int i = t; i < HW_; i += 256) sa_s[i] = sa[(size_t)nk * HW_ + i];
    __syncthreads();
    for (int p = t; p < P_; p += 256) {
        const int hp = p / WP_, wp = p - hp * WP_;
        float bs = 0.f;
#pragma unroll
        for (int dh = 0; dh < 4; ++dh) {
            const float* r = &sa_s[(hp + dh) * W_ + wp];
            bs += r[0] + r[1] + r[2] + r[3];
        }
        const float sc = inv1[(size_t)nk * P_ + p] * inv2[n * P_ + p];
        scl_s[p] = sc;
        t2_s[p]  = bs * sc;
    }

    const float* xb = xnT + (size_t)n * C_ * HW_;
    float* ob = outl + (size_t)nk * CP_;

    for (int g = 0; g < 8; ++g) {
        const int c0 = cq * 32 + g * 4;
        const float* x0 = xb + (size_t)(c0 + 0) * HW_;
        const float* x1 = xb + (size_t)(c0 + 1) * HW_;
        const float* x2 = xb + (size_t)(c0 + 2) * HW_;
        const float* x3 = xb + (size_t)(c0 + 3) * HW_;
        __syncthreads();   // prior group's cs_s readers done; scl/t2 visible (g=0)
        for (int i = t; i < HP_ * W_; i += 256) {
            const float s0 = sa_s[i];
            const float s1 = sa_s[i + W_];
            const float s2 = sa_s[i + 2 * W_];
            const float s3 = sa_s[i + 3 * W_];
            cs_s[i] = make_float4(
                s0 * x0[i] + s1 * x0[i + W_] + s2 * x0[i + 2 * W_] + s3 * x0[i + 3 * W_],
                s0 * x1[i] + s1 * x1[i + W_] + s2 * x1[i + 2 * W_] + s3 * x1[i + 3 * W_],
                s0 * x2[i] + s1 * x2[i + W_] + s2 * x2[i + 2 * W_] + s3 * x2[i + 3 * W_],
                s0 * x3[i] + s1 * x3[i + W_] + s2 * x3[i + 2 * W_] + s3 * x3[i + 3 * W_]);
        }
        __syncthreads();
        const float4 ce = *reinterpret_cast<const float4*>(&cent[k * C_ + c0]);
#pragma unroll
        for (int pi = 0; pi < 4; ++pi) {
            const int p = t + pi * 256;
            if (p < P_) {
                const int hp = p / WP_, wp = p - hp * WP_;
                const int base = hp * W_ + wp;
                const float4 s0 = cs_s[base], s1 = cs_s[base + 1],
                             s2 = cs_s[base + 2], s3 = cs_s[base + 3];
                const float sc = scl_s[p];
                const float tt = t2_s[p];
                ob[(size_t)(c0 + 0) * P_ + p] = (s0.x + s1.x + s2.x + s3.x) * sc - ce.x * tt;
                ob[(size_t)(c0 + 1) * P_ + p] = (s0.y + s1.y + s2.y + s3.y) * sc - ce.y * tt;
                ob[(size_t)(c0 + 2) * P_ + p] = (s0.z + s1.z + s2.z + s3.z) * sc - ce.z * tt;
                ob[(size_t)(c0 + 3) * P_ + p] = (s0.w + s1.w + s2.w + s3.w) * sc - ce.w * tt;
            }
        }
    }
}

// ---------------------------------------------------------------------------
extern "C" void kernel_launch(void* const* d_in, const int* in_sizes, int n_in,
                              void* d_out, int out_size, void* d_ws, size_t ws_size,
                              hipStream_t stream)
{
    const float* x      = (const float*)d_in[0];
    const float* conv_w = (const float*)d_in[1];
    const float* cent   = (const float*)d_in[2];
    float* out = (float*)d_out;
    float* ws  = (float*)d_ws;

    // workspace layout (floats)
    float* xnT  = ws;                       // 614400
    float* xnP  = ws + 614400;              // 614400
    float* sa   = ws + 1228800;             // 307200
    float* vg_u = ws + 1536000;             // 32768
    float* vg_r = ws + 1568768;             // 256
    float* nsqp = ws + 1569024;             // 1022976
    float* inv1 = ws + 2592000;             // 255744
    float* rloc = ws + 2847744;             // 255744
    float* inv2 = ws + 3103488;             // 3996

    float* outl = out + (size_t)N_ * KC_;   // output 1 region

    k1_norm_softmax<<<N_ * H_, 256, 0, stream>>>(x, conv_w, xnT, xnP, sa);
    k2_vg<<<N_ * K_, 128, 0, stream>>>(sa, xnP, cent, vg_u, vg_r);
    k3_vg_fin<<<N_, 256, 0, stream>>>(vg_u, vg_r, out);
    k4_norm<<<N_ * K_ * 4, 256, 0, stream>>>(sa, xnT, cent, nsqp);
    k5_combine<<<N_ * K_, 256, 0, stream>>>(nsqp, inv1, rloc);
    k6_inv2<<<N_ * 4, 256, 0, stream>>>(rloc, inv2);
    k7_write<<<N_ * K_ * 4, 256, 0, stream>>>(sa, xnT, cent, inv1, inv2, outl);
}

// Round 4
// 129.901 us; speedup vs baseline: 1.4452x; 1.0499x over previous
//
#include <hip/hip_runtime.h>
#include <math.h>

#define EPSV 1e-12f

namespace {
constexpr int N_  = 4;
constexpr int C_  = 128;
constexpr int H_  = 30;
constexpr int W_  = 40;
constexpr int K_  = 64;
constexpr int HW_ = H_ * W_;        // 1200
constexpr int HP_ = 27;             // H+1-4
constexpr int WP_ = 37;             // W+1-4
constexpr int P_  = HP_ * WP_;      // 999
constexpr int KC_ = K_ * C_;        // 8192
constexpr int CP_ = C_ * P_;        // 127872 floats per (n,k) slab
constexpr int CS_ = HP_ * W_;       // 1080 colsum rows
constexpr int SL_ = CS_ / 4;        // 270 vector slots
}

static __device__ __forceinline__ float4 ld4(const float* p) {
    return *reinterpret_cast<const float4*>(p);
}

// ---------------------------------------------------------------------------
// K1: per (n,h) row — L2-normalize x over channels, write xn in two layouts,
//     compute conv scores + softmax -> sa  (layout [n][k][pix])
// ---------------------------------------------------------------------------
__global__ __launch_bounds__(256) void k1_norm_softmax(
    const float* __restrict__ x, const float* __restrict__ conv_w,
    float* __restrict__ xnT, float* __restrict__ xnP, float* __restrict__ sa)
{
    __shared__ float xrow[C_ * W_];   // [c][w]
    __shared__ float conv_s[K_ * C_]; // [k][c]
    __shared__ float invn[W_];
    __shared__ float s_s[K_ * W_];    // [k][w]

    const int b = blockIdx.x;         // n*H + h
    const int n = b / H_, h = b - n * H_;
    const int t = threadIdx.x;

    for (int i = t; i < C_ * W_; i += 256) {
        const int c = i / W_, w = i - c * W_;
        xrow[i] = x[(size_t)(n * C_ + c) * HW_ + h * W_ + w];
    }
    for (int i = t; i < K_ * C_; i += 256) conv_s[i] = conv_w[i];
    __syncthreads();

    if (t < W_) {
        float s = 0.f;
        for (int c = 0; c < C_; ++c) { const float v = xrow[c * W_ + t]; s += v * v; }
        invn[t] = 1.f / fmaxf(sqrtf(s), EPSV);
    }
    __syncthreads();

    for (int i = t; i < C_ * W_; i += 256) {
        const int c = i / W_, w = i - c * W_;
        const float v = xrow[i] * invn[w];
        xrow[i] = v;
        xnT[(size_t)(n * C_ + c) * HW_ + h * W_ + w] = v;
    }
    __syncthreads();

    for (int i = t; i < W_ * C_; i += 256) {
        const int w = i / C_, c = i - w * C_;
        xnP[((size_t)n * HW_ + h * W_ + w) * C_ + c] = xrow[c * W_ + w];
    }

    for (int d = t; d < K_ * W_; d += 256) {
        const int k = d / W_, w = d - k * W_;
        const float* cw = &conv_s[k * C_];
        float s = 0.f;
        for (int c = 0; c < C_; ++c) s += cw[c] * xrow[c * W_ + w];
        s_s[d] = s;
    }
    __syncthreads();

    if (t < W_) {
        const int w = t;
        float m = -1e30f;
        for (int k = 0; k < K_; ++k) m = fmaxf(m, s_s[k * W_ + w]);
        float sum = 0.f;
        for (int k = 0; k < K_; ++k) sum += expf(s_s[k * W_ + w] - m);
        const float inv = 1.f / sum;
        for (int k = 0; k < K_; ++k)
            sa[(size_t)(n * K_ + k) * HW_ + h * W_ + w] = expf(s_s[k * W_ + w] - m) * inv;
    }
}

// ---------------------------------------------------------------------------
// K2: vlad_global per (n,k) — 256 threads: channel c = t&127, pixel-half
//     = t>>7; LDS combine then wave reduce.
// ---------------------------------------------------------------------------
__global__ __launch_bounds__(256) void k2_vg(
    const float* __restrict__ sa, const float* __restrict__ xnP,
    const float* __restrict__ cent, float* __restrict__ vg_u,
    float* __restrict__ vg_r)
{
    const int b = blockIdx.x;         // n*K + k
    const int n = b >> 6, k = b & 63;
    const int t = threadIdx.x;
    const int c = t & 127, half = t >> 7;
    constexpr int HHW = HW_ / 2;      // 600

    const float* sarow = &sa[(size_t)b * HW_ + half * HHW];
    const float* xp = &xnP[((size_t)n * HW_ + half * HHW) * C_ + c];
    float g0 = 0.f, g1 = 0.f, g2 = 0.f, g3 = 0.f;
    float b0 = 0.f, b1 = 0.f, b2 = 0.f, b3 = 0.f;
    for (int pix = 0; pix < HHW; pix += 4) {
        const float s0 = sarow[pix + 0], s1 = sarow[pix + 1];
        const float s2 = sarow[pix + 2], s3 = sarow[pix + 3];
        g0 += s0 * xp[(size_t)(pix + 0) * C_];
        g1 += s1 * xp[(size_t)(pix + 1) * C_];
        g2 += s2 * xp[(size_t)(pix + 2) * C_];
        g3 += s3 * xp[(size_t)(pix + 3) * C_];
        b0 += s0; b1 += s1; b2 += s2; b3 += s3;
    }
    const float g  = (g0 + g1) + (g2 + g3);
    const float bs = (b0 + b1) + (b2 + b3);

    __shared__ float gs[256], bss[256];
    __shared__ float red[2];
    gs[t] = g; bss[t] = bs;
    __syncthreads();

    float vg = 0.f;
    if (t < 128) {
        vg = (gs[t] + gs[t + 128]) - cent[k * C_ + c] * (bss[t] + bss[t + 128]);
        float nsq = vg * vg;
        for (int off = 32; off >= 1; off >>= 1) nsq += __shfl_down(nsq, off);
        if ((t & 63) == 0) red[t >> 6] = nsq;
    }
    __syncthreads();
    const float tot  = red[0] + red[1];
    const float norm = sqrtf(tot);
    const float iv   = 1.f / fmaxf(norm, EPSV);
    if (t < 128) vg_u[(size_t)b * C_ + t] = vg * iv;
    if (t == 0) { const float rr = norm * iv; vg_r[b] = rr * rr; }
}

// K3: finalize vlad_global
__global__ __launch_bounds__(256) void k3_vg_fin(
    const float* __restrict__ vg_u, const float* __restrict__ vg_r,
    float* __restrict__ out)
{
    const int n = blockIdx.x;
    const int t = threadIdx.x;
    __shared__ float inv2s;
    if (t == 0) {
        float s = 0.f;
        for (int k = 0; k < K_; ++k) s += vg_r[n * K_ + k];
        inv2s = 1.f / fmaxf(sqrtf(s), EPSV);
    }
    __syncthreads();
    const float inv2 = inv2s;
    for (int i = t; i < KC_; i += 256)
        out[(size_t)n * KC_ + i] = vg_u[(size_t)n * KC_ + i] * inv2;
}

// ---------------------------------------------------------------------------
// Vectorized fused colsum: thread owns 4 consecutive linear colsum pixels.
// 16 dwordx4 global loads + 4 b128 LDS reads + 64 FMA + 4 b128 writes / slot.
// ---------------------------------------------------------------------------
#define COLSUM_VEC(cs_s, sa_s, x0, x1, x2, x3)                                  \
    for (int s = t; s < SL_; s += 256) {                                        \
        const int i = s * 4;                                                    \
        const float4 sa0 = ld4(&sa_s[i]);                                       \
        const float4 sa1 = ld4(&sa_s[i + W_]);                                  \
        const float4 sa2 = ld4(&sa_s[i + 2 * W_]);                              \
        const float4 sa3 = ld4(&sa_s[i + 3 * W_]);                              \
        float acc[4][4];                                                        \
        const float* xc[4] = {x0, x1, x2, x3};                                  \
        _Pragma("unroll")                                                       \
        for (int ch = 0; ch < 4; ++ch) {                                        \
            const float4 a0 = ld4(xc[ch] + i);                                  \
            const float4 a1 = ld4(xc[ch] + i + W_);                             \
            const float4 a2 = ld4(xc[ch] + i + 2 * W_);                         \
            const float4 a3 = ld4(xc[ch] + i + 3 * W_);                         \
            acc[0][ch] = sa0.x * a0.x + sa1.x * a1.x + sa2.x * a2.x + sa3.x * a3.x; \
            acc[1][ch] = sa0.y * a0.y + sa1.y * a1.y + sa2.y * a2.y + sa3.y * a3.y; \
            acc[2][ch] = sa0.z * a0.z + sa1.z * a1.z + sa2.z * a2.z + sa3.z * a3.z; \
            acc[3][ch] = sa0.w * a0.w + sa1.w * a1.w + sa2.w * a2.w + sa3.w * a3.w; \
        }                                                                       \
        _Pragma("unroll")                                                       \
        for (int q = 0; q < 4; ++q)                                             \
            cs_s[i + q] = make_float4(acc[q][0], acc[q][1], acc[q][2], acc[q][3]); \
    }

// ---------------------------------------------------------------------------
// K4n: NORM-ONLY box-sum pass — writes only nsqp (4 MB), no output store.
// ---------------------------------------------------------------------------
__global__ __launch_bounds__(256) void k4_norm(
    const float* __restrict__ sa, const float* __restrict__ xnT,
    const float* __restrict__ cent, float* __restrict__ nsqp)
{
    __shared__ float  sa_s[HW_];
    __shared__ float  B_s[P_];
    __shared__ float4 cs_s[CS_];

    const int b  = blockIdx.x;            // ((n*K + k)*4 + cq)
    const int cq = b & 3;
    const int nk = b >> 2;
    const int n  = nk >> 6, k = nk & 63;
    const int t  = threadIdx.x;

    for (int i = t; i < HW_; i += 256) sa_s[i] = sa[(size_t)nk * HW_ + i];
    __syncthreads();
    for (int p = t; p < P_; p += 256) {
        const int hp = p / WP_, wp = p - hp * WP_;
        float bs = 0.f;
#pragma unroll
        for (int dh = 0; dh < 4; ++dh) {
            const float* r = &sa_s[(hp + dh) * W_ + wp];
            bs += r[0] + r[1] + r[2] + r[3];
        }
        B_s[p] = bs;
    }

    float nsq0 = 0.f, nsq1 = 0.f, nsq2 = 0.f, nsq3 = 0.f;
    const float* xb = xnT + (size_t)n * C_ * HW_;

    for (int g = 0; g < 8; ++g) {
        const int c0 = cq * 32 + g * 4;
        const float* x0 = xb + (size_t)(c0 + 0) * HW_;
        const float* x1 = xb + (size_t)(c0 + 1) * HW_;
        const float* x2 = xb + (size_t)(c0 + 2) * HW_;
        const float* x3 = xb + (size_t)(c0 + 3) * HW_;
        __syncthreads();   // prior group's cs_s readers done; B_s visible (g=0)
        COLSUM_VEC(cs_s, sa_s, x0, x1, x2, x3)
        __syncthreads();
        const float4 ce = ld4(&cent[k * C_ + c0]);
#pragma unroll
        for (int pi = 0; pi < 4; ++pi) {
            const int p = t + pi * 256;
            if (p < P_) {
                const int hp = p / WP_, wp = p - hp * WP_;
                const int base = hp * W_ + wp;
                const float4 s0 = cs_s[base], s1 = cs_s[base + 1],
                             s2 = cs_s[base + 2], s3 = cs_s[base + 3];
                const float Bv = B_s[p];
                const float ux = (s0.x + s1.x + s2.x + s3.x) - ce.x * Bv;
                const float uy = (s0.y + s1.y + s2.y + s3.y) - ce.y * Bv;
                const float uz = (s0.z + s1.z + s2.z + s3.z) - ce.z * Bv;
                const float uw = (s0.w + s1.w + s2.w + s3.w) - ce.w * Bv;
                const float add = ux * ux + uy * uy + uz * uz + uw * uw;
                if      (pi == 0) nsq0 += add;
                else if (pi == 1) nsq1 += add;
                else if (pi == 2) nsq2 += add;
                else              nsq3 += add;
            }
        }
    }
#pragma unroll
    for (int pi = 0; pi < 4; ++pi) {
        const int p = t + pi * 256;
        if (p < P_) {
            const float v = (pi == 0 ? nsq0 : pi == 1 ? nsq1 : pi == 2 ? nsq2 : nsq3);
            nsqp[(size_t)b * P_ + p] = v * 0.00390625f;  // (1/16)^2
        }
    }
}

// K5: combine 4 channel-quarter partials -> per (n,k,p) scaled inv-norm
//     (0.0625 folded in) + ratio for the second norm.
__global__ __launch_bounds__(256) void k5_combine(
    const float* __restrict__ nsqp, float* __restrict__ inv1,
    float* __restrict__ rloc)
{
    const int nk = blockIdx.x;
    const int t  = threadIdx.x;
    for (int p = t; p < P_; p += 256) {
        const float s = nsqp[(size_t)(nk * 4 + 0) * P_ + p]
                      + nsqp[(size_t)(nk * 4 + 1) * P_ + p]
                      + nsqp[(size_t)(nk * 4 + 2) * P_ + p]
                      + nsqp[(size_t)(nk * 4 + 3) * P_ + p];
        const float norm = sqrtf(s);
        const float iv = 1.f / fmaxf(norm, EPSV);
        inv1[(size_t)nk * P_ + p] = iv * 0.0625f;   // fold 1/16
        const float rr = norm * iv;
        rloc[(size_t)nk * P_ + p] = rr * rr;
    }
}

// K6: inv2[n,p] = 1/max(sqrt(sum_k r),EPS)
__global__ __launch_bounds__(256) void k6_inv2(
    const float* __restrict__ rloc, float* __restrict__ inv2)
{
    const int n = blockIdx.x >> 2;
    const int p = (blockIdx.x & 3) * 256 + threadIdx.x;
    if (p < P_) {
        float s = 0.f;
        for (int k = 0; k < K_; ++k) s += rloc[(size_t)(n * K_ + k) * P_ + p];
        inv2[n * P_ + p] = 1.f / fmaxf(sqrtf(s), EPSV);
    }
}

// ---------------------------------------------------------------------------
// K7w: WRITE pass — recompute fused box-sums, apply scl = inv1*inv2 on the
//      fly, write output1 exactly once (fully coalesced rows).
// ---------------------------------------------------------------------------
__global__ __launch_bounds__(256) void k7_write(
    const float* __restrict__ sa, const float* __restrict__ xnT,
    const float* __restrict__ cent, const float* __restrict__ inv1,
    const float* __restrict__ inv2, float* __restrict__ outl)
{
    __shared__ float  sa_s[HW_];
    __shared__ float  scl_s[P_];
    __shared__ float  t2_s[P_];
    __shared__ float4 cs_s[CS_];

    const int b  = blockIdx.x;            // ((n*K + k)*4 + cq)
    const int cq = b & 3;
    const int nk = b >> 2;
    const int n  = nk >> 6, k = nk & 63;
    const int t  = threadIdx.x;

    for (int i = t; i < HW_; i += 256) sa_s[i] = sa[(size_t)nk * HW_ + i];
    __syncthreads();
    for (int p = t; p < P_; p += 256) {
        const int hp = p / WP_, wp = p - hp * WP_;
        float bs = 0.f;
#pragma unroll
        for (int dh = 0; dh < 4; ++dh) {
            const float* r = &sa_s[(hp + dh) * W_ + wp];
            bs += r[0] + r[1] + r[2] + r[3];
        }
        const float sc = inv1[(size_t)nk * P_ + p] * inv2[n * P_ + p];
        scl_s[p] = sc;
        t2_s[p]  = bs * sc;
    }

    const float* xb = xnT + (size_t)n * C_ * HW_;
    float* ob = outl + (size_t)nk * CP_;

    for (int g = 0; g < 8; ++g) {
        const int c0 = cq * 32 + g * 4;
        const float* x0 = xb + (size_t)(c0 + 0) * HW_;
        const float* x1 = xb + (size_t)(c0 + 1) * HW_;
        const float* x2 = xb + (size_t)(c0 + 2) * HW_;
        const float* x3 = xb + (size_t)(c0 + 3) * HW_;
        __syncthreads();   // prior group's cs_s readers done; scl/t2 visible (g=0)
        COLSUM_VEC(cs_s, sa_s, x0, x1, x2, x3)
        __syncthreads();
        const float4 ce = ld4(&cent[k * C_ + c0]);
#pragma unroll
        for (int pi = 0; pi < 4; ++pi) {
            const int p = t + pi * 256;
            if (p < P_) {
                const int hp = p / WP_, wp = p - hp * WP_;
                const int base = hp * W_ + wp;
                const float4 s0 = cs_s[base], s1 = cs_s[base + 1],
                             s2 = cs_s[base + 2], s3 = cs_s[base + 3];
                const float sc = scl_s[p];
                const float tt = t2_s[p];
                ob[(size_t)(c0 + 0) * P_ + p] = (s0.x + s1.x + s2.x + s3.x) * sc - ce.x * tt;
                ob[(size_t)(c0 + 1) * P_ + p] = (s0.y + s1.y + s2.y + s3.y) * sc - ce.y * tt;
                ob[(size_t)(c0 + 2) * P_ + p] = (s0.z + s1.z + s2.z + s3.z) * sc - ce.z * tt;
                ob[(size_t)(c0 + 3) * P_ + p] = (s0.w + s1.w + s2.w + s3.w) * sc - ce.w * tt;
            }
        }
    }
}

// ---------------------------------------------------------------------------
extern "C" void kernel_launch(void* const* d_in, const int* in_sizes, int n_in,
                              void* d_out, int out_size, void* d_ws, size_t ws_size,
                              hipStream_t stream)
{
    const float* x      = (const float*)d_in[0];
    const float* conv_w = (const float*)d_in[1];
    const float* cent   = (const float*)d_in[2];
    float* out = (float*)d_out;
    float* ws  = (float*)d_ws;

    // workspace layout (floats)
    float* xnT  = ws;                       // 614400
    float* xnP  = ws + 614400;              // 614400
    float* sa   = ws + 1228800;             // 307200
    float* vg_u = ws + 1536000;             // 32768
    float* vg_r = ws + 1568768;             // 256
    float* nsqp = ws + 1569024;             // 1022976
    float* inv1 = ws + 2592000;             // 255744
    float* rloc = ws + 2847744;             // 255744
    float* inv2 = ws + 3103488;             // 3996

    float* outl = out + (size_t)N_ * KC_;   // output 1 region

    k1_norm_softmax<<<N_ * H_, 256, 0, stream>>>(x, conv_w, xnT, xnP, sa);
    k2_vg<<<N_ * K_, 256, 0, stream>>>(sa, xnP, cent, vg_u, vg_r);
    k3_vg_fin<<<N_, 256, 0, stream>>>(vg_u, vg_r, out);
    k4_norm<<<N_ * K_ * 4, 256, 0, stream>>>(sa, xnT, cent, nsqp);
    k5_combine<<<N_ * K_, 256, 0, stream>>>(nsqp, inv1, rloc);
    k6_inv2<<<N_ * 4, 256, 0, stream>>>(rloc, inv2);
    k7_write<<<N_ * K_ * 4, 256, 0, stream>>>(sa, xnT, cent, inv1, inv2, outl);
}

// Round 5
// 126.114 us; speedup vs baseline: 1.4886x; 1.0300x over previous
//
#include <hip/hip_runtime.h>
#include <math.h>

#define EPSV 1e-12f

namespace {
constexpr int N_  = 4;
constexpr int C_  = 128;
constexpr int H_  = 30;
constexpr int W_  = 40;
constexpr int K_  = 64;
constexpr int HW_ = H_ * W_;        // 1200
constexpr int HP_ = 27;             // H+1-4
constexpr int WP_ = 37;             // W+1-4
constexpr int P_  = HP_ * WP_;      // 999
constexpr int KC_ = K_ * C_;        // 8192
constexpr int CP_ = C_ * P_;        // 127872 floats per (n,k) slab
constexpr int CS_ = HP_ * W_;       // 1080 colsum rows
constexpr int SL_ = CS_ / 4;        // 270 vector slots (NOTE: 270*4 dwords ≡ 24 mod 32
                                    // -> q-rows of cs_q land on distinct bank offsets;
                                    // do NOT pad to 272, that aliases all rows to bank 0)
}

static __device__ __forceinline__ float4 ld4(const float* p) {
    return *reinterpret_cast<const float4*>(p);
}

// ---------------------------------------------------------------------------
// K1: per (n,h) row — L2-normalize x over channels, write xn in two layouts,
//     compute conv scores + softmax -> sa  (layout [n][k][pix])
// ---------------------------------------------------------------------------
__global__ __launch_bounds__(256) void k1_norm_softmax(
    const float* __restrict__ x, const float* __restrict__ conv_w,
    float* __restrict__ xnT, float* __restrict__ xnP, float* __restrict__ sa)
{
    __shared__ float xrow[C_ * W_];   // [c][w]
    __shared__ float conv_s[K_ * C_]; // [k][c]
    __shared__ float invn[W_];
    __shared__ float s_s[K_ * W_];    // [k][w]

    const int b = blockIdx.x;         // n*H + h
    const int n = b / H_, h = b - n * H_;
    const int t = threadIdx.x;

    for (int i = t; i < C_ * W_; i += 256) {
        const int c = i / W_, w = i - c * W_;
        xrow[i] = x[(size_t)(n * C_ + c) * HW_ + h * W_ + w];
    }
    for (int i = t; i < K_ * C_; i += 256) conv_s[i] = conv_w[i];
    __syncthreads();

    if (t < W_) {
        float s = 0.f;
        for (int c = 0; c < C_; ++c) { const float v = xrow[c * W_ + t]; s += v * v; }
        invn[t] = 1.f / fmaxf(sqrtf(s), EPSV);
    }
    __syncthreads();

    for (int i = t; i < C_ * W_; i += 256) {
        const int c = i / W_, w = i - c * W_;
        const float v = xrow[i] * invn[w];
        xrow[i] = v;
        xnT[(size_t)(n * C_ + c) * HW_ + h * W_ + w] = v;
    }
    __syncthreads();

    for (int i = t; i < W_ * C_; i += 256) {
        const int w = i / C_, c = i - w * C_;
        xnP[((size_t)n * HW_ + h * W_ + w) * C_ + c] = xrow[c * W_ + w];
    }

    for (int d = t; d < K_ * W_; d += 256) {
        const int k = d / W_, w = d - k * W_;
        const float* cw = &conv_s[k * C_];
        float s = 0.f;
        for (int c = 0; c < C_; ++c) s += cw[c] * xrow[c * W_ + w];
        s_s[d] = s;
    }
    __syncthreads();

    if (t < W_) {
        const int w = t;
        float m = -1e30f;
        for (int k = 0; k < K_; ++k) m = fmaxf(m, s_s[k * W_ + w]);
        float sum = 0.f;
        for (int k = 0; k < K_; ++k) sum += expf(s_s[k * W_ + w] - m);
        const float inv = 1.f / sum;
        for (int k = 0; k < K_; ++k)
            sa[(size_t)(n * K_ + k) * HW_ + h * W_ + w] = expf(s_s[k * W_ + w] - m) * inv;
    }
}

// ---------------------------------------------------------------------------
// K2: vlad_global per (n,k) — 1024 threads: channel c = t&127, pixel-eighth
//     = t>>7 (150 px each); 16 waves/CU for latency hiding; LDS tree combine.
// ---------------------------------------------------------------------------
__global__ __launch_bounds__(1024) void k2_vg(
    const float* __restrict__ sa, const float* __restrict__ xnP,
    const float* __restrict__ cent, float* __restrict__ vg_u,
    float* __restrict__ vg_r)
{
    const int b = blockIdx.x;         // n*K + k
    const int n = b >> 6, k = b & 63;
    const int t = threadIdx.x;
    const int c = t & 127, eighth = t >> 7;
    constexpr int CHW = HW_ / 8;      // 150

    const float* sarow = &sa[(size_t)b * HW_ + eighth * CHW];
    const float* xp = &xnP[((size_t)n * HW_ + eighth * CHW) * C_ + c];
    float g0 = 0.f, g1 = 0.f, b0 = 0.f, b1 = 0.f;
    for (int pix = 0; pix < CHW; pix += 2) {
        const float s0 = sarow[pix + 0], s1 = sarow[pix + 1];
        g0 += s0 * xp[(size_t)(pix + 0) * C_];
        g1 += s1 * xp[(size_t)(pix + 1) * C_];
        b0 += s0; b1 += s1;
    }
    const float g  = g0 + g1;
    const float bs = b0 + b1;

    __shared__ float gs[1024], bss[1024];
    __shared__ float red[2];
    gs[t] = g; bss[t] = bs;
    __syncthreads();

    float vg = 0.f;
    if (t < 128) {
        float gt = 0.f, bt = 0.f;
#pragma unroll
        for (int e = 0; e < 8; ++e) { gt += gs[t + 128 * e]; bt += bss[t + 128 * e]; }
        vg = gt - cent[k * C_ + t] * bt;
        float nsq = vg * vg;
        for (int off = 32; off >= 1; off >>= 1) nsq += __shfl_down(nsq, off);
        if ((t & 63) == 0) red[t >> 6] = nsq;
    }
    __syncthreads();
    const float tot  = red[0] + red[1];
    const float norm = sqrtf(tot);
    const float iv   = 1.f / fmaxf(norm, EPSV);
    if (t < 128) vg_u[(size_t)b * C_ + t] = vg * iv;
    if (t == 0) { const float rr = norm * iv; vg_r[b] = rr * rr; }
}

// K3: finalize vlad_global
__global__ __launch_bounds__(256) void k3_vg_fin(
    const float* __restrict__ vg_u, const float* __restrict__ vg_r,
    float* __restrict__ out)
{
    const int n = blockIdx.x;
    const int t = threadIdx.x;
    __shared__ float inv2s;
    if (t == 0) {
        float s = 0.f;
        for (int k = 0; k < K_; ++k) s += vg_r[n * K_ + k];
        inv2s = 1.f / fmaxf(sqrtf(s), EPSV);
    }
    __syncthreads();
    const float inv2 = inv2s;
    for (int i = t; i < KC_; i += 256)
        out[(size_t)n * KC_ + i] = vg_u[(size_t)n * KC_ + i] * inv2;
}

// ---------------------------------------------------------------------------
// Vectorized fused colsum with TRANSPOSED output cs_q[q][s]:
//   writes are lane-contiguous (stride 16B, conflict-free) vs the old
//   cs_s[4s+q] pattern (64B stride = 32-way bank conflict on every write).
// ---------------------------------------------------------------------------
#define COLSUM_VEC_T(cs_q, sa_s, x0, x1, x2, x3)                                \
    for (int s = t; s < SL_; s += 256) {                                        \
        const int i = s * 4;                                                    \
        const float4 sa0 = ld4(&sa_s[i]);                                       \
        const float4 sa1 = ld4(&sa_s[i + W_]);                                  \
        const float4 sa2 = ld4(&sa_s[i + 2 * W_]);                              \
        const float4 sa3 = ld4(&sa_s[i + 3 * W_]);                              \
        float acc[4][4];                                                        \
        const float* xc[4] = {x0, x1, x2, x3};                                  \
        _Pragma("unroll")                                                       \
        for (int ch = 0; ch < 4; ++ch) {                                        \
            const float4 a0 = ld4(xc[ch] + i);                                  \
            const float4 a1 = ld4(xc[ch] + i + W_);                             \
            const float4 a2 = ld4(xc[ch] + i + 2 * W_);                         \
            const float4 a3 = ld4(xc[ch] + i + 3 * W_);                         \
            acc[0][ch] = sa0.x * a0.x + sa1.x * a1.x + sa2.x * a2.x + sa3.x * a3.x; \
            acc[1][ch] = sa0.y * a0.y + sa1.y * a1.y + sa2.y * a2.y + sa3.y * a3.y; \
            acc[2][ch] = sa0.z * a0.z + sa1.z * a1.z + sa2.z * a2.z + sa3.z * a3.z; \
            acc[3][ch] = sa0.w * a0.w + sa1.w * a1.w + sa2.w * a2.w + sa3.w * a3.w; \
        }                                                                       \
        _Pragma("unroll")                                                       \
        for (int q = 0; q < 4; ++q)                                             \
            cs_q[q][s] = make_float4(acc[q][0], acc[q][1], acc[q][2], acc[q][3]); \
    }

// fetch colsum float4 (channels) for linear colsum pixel e
static __device__ __forceinline__ float4 csget(const float4 cs_q[4][SL_], int e) {
    return cs_q[e & 3][e >> 2];
}

// ---------------------------------------------------------------------------
// K4n: NORM-ONLY box-sum pass — writes only nsqp (4 MB), no output store.
// ---------------------------------------------------------------------------
__global__ __launch_bounds__(256) void k4_norm(
    const float* __restrict__ sa, const float* __restrict__ xnT,
    const float* __restrict__ cent, float* __restrict__ nsqp)
{
    __shared__ float  sa_s[HW_];
    __shared__ float  B_s[P_];
    __shared__ float4 cs_q[4][SL_];

    const int b  = blockIdx.x;            // ((n*K + k)*4 + cq)
    const int cq = b & 3;
    const int nk = b >> 2;
    const int n  = nk >> 6, k = nk & 63;
    const int t  = threadIdx.x;

    for (int i = t; i < HW_; i += 256) sa_s[i] = sa[(size_t)nk * HW_ + i];
    __syncthreads();
    for (int p = t; p < P_; p += 256) {
        const int hp = p / WP_, wp = p - hp * WP_;
        float bs = 0.f;
#pragma unroll
        for (int dh = 0; dh < 4; ++dh) {
            const float* r = &sa_s[(hp + dh) * W_ + wp];
            bs += r[0] + r[1] + r[2] + r[3];
        }
        B_s[p] = bs;
    }

    float nsq0 = 0.f, nsq1 = 0.f, nsq2 = 0.f, nsq3 = 0.f;
    const float* xb = xnT + (size_t)n * C_ * HW_;

    for (int g = 0; g < 8; ++g) {
        const int c0 = cq * 32 + g * 4;
        const float* x0 = xb + (size_t)(c0 + 0) * HW_;
        const float* x1 = xb + (size_t)(c0 + 1) * HW_;
        const float* x2 = xb + (size_t)(c0 + 2) * HW_;
        const float* x3 = xb + (size_t)(c0 + 3) * HW_;
        __syncthreads();   // prior group's cs_q readers done; B_s visible (g=0)
        COLSUM_VEC_T(cs_q, sa_s, x0, x1, x2, x3)
        __syncthreads();
        const float4 ce = ld4(&cent[k * C_ + c0]);
#pragma unroll
        for (int pi = 0; pi < 4; ++pi) {
            const int p = t + pi * 256;
            if (p < P_) {
                const int hp = p / WP_, wp = p - hp * WP_;
                const int base = hp * W_ + wp;
                const float4 s0 = csget(cs_q, base);
                const float4 s1 = csget(cs_q, base + 1);
                const float4 s2 = csget(cs_q, base + 2);
                const float4 s3 = csget(cs_q, base + 3);
                const float Bv = B_s[p];
                const float ux = (s0.x + s1.x + s2.x + s3.x) - ce.x * Bv;
                const float uy = (s0.y + s1.y + s2.y + s3.y) - ce.y * Bv;
                const float uz = (s0.z + s1.z + s2.z + s3.z) - ce.z * Bv;
                const float uw = (s0.w + s1.w + s2.w + s3.w) - ce.w * Bv;
                const float add = ux * ux + uy * uy + uz * uz + uw * uw;
                if      (pi == 0) nsq0 += add;
                else if (pi == 1) nsq1 += add;
                else if (pi == 2) nsq2 += add;
                else              nsq3 += add;
            }
        }
    }
#pragma unroll
    for (int pi = 0; pi < 4; ++pi) {
        const int p = t + pi * 256;
        if (p < P_) {
            const float v = (pi == 0 ? nsq0 : pi == 1 ? nsq1 : pi == 2 ? nsq2 : nsq3);
            nsqp[(size_t)b * P_ + p] = v * 0.00390625f;  // (1/16)^2
        }
    }
}

// K5: combine 4 channel-quarter partials -> per (n,k,p) scaled inv-norm
//     (0.0625 folded in) + ratio for the second norm.
__global__ __launch_bounds__(256) void k5_combine(
    const float* __restrict__ nsqp, float* __restrict__ inv1,
    float* __restrict__ rloc)
{
    const int nk = blockIdx.x;
    const int t  = threadIdx.x;
    for (int p = t; p < P_; p += 256) {
        const float s = nsqp[(size_t)(nk * 4 + 0) * P_ + p]
                      + nsqp[(size_t)(nk * 4 + 1) * P_ + p]
                      + nsqp[(size_t)(nk * 4 + 2) * P_ + p]
                      + nsqp[(size_t)(nk * 4 + 3) * P_ + p];
        const float norm = sqrtf(s);
        const float iv = 1.f / fmaxf(norm, EPSV);
        inv1[(size_t)nk * P_ + p] = iv * 0.0625f;   // fold 1/16
        const float rr = norm * iv;
        rloc[(size_t)nk * P_ + p] = rr * rr;
    }
}

// K6: inv2[n,p] = 1/max(sqrt(sum_k r),EPS)
__global__ __launch_bounds__(256) void k6_inv2(
    const float* __restrict__ rloc, float* __restrict__ inv2)
{
    const int n = blockIdx.x >> 2;
    const int p = (blockIdx.x & 3) * 256 + threadIdx.x;
    if (p < P_) {
        float s = 0.f;
        for (int k = 0; k < K_; ++k) s += rloc[(size_t)(n * K_ + k) * P_ + p];
        inv2[n * P_ + p] = 1.f / fmaxf(sqrtf(s), EPSV);
    }
}

// ---------------------------------------------------------------------------
// K7w: WRITE pass — recompute fused box-sums, apply scl = inv1*inv2 on the
//      fly, write output1 exactly once (fully coalesced rows).
// ---------------------------------------------------------------------------
__global__ __launch_bounds__(256) void k7_write(
    const float* __restrict__ sa, const float* __restrict__ xnT,
    const float* __restrict__ cent, const float* __restrict__ inv1,
    const float* __restrict__ inv2, float* __restrict__ outl)
{
    __shared__ float  sa_s[HW_];
    __shared__ float  scl_s[P_];
    __shared__ float  t2_s[P_];
    __shared__ float4 cs_q[4][SL_];

    const int b  = blockIdx.x;            // ((n*K + k)*4 + cq)
    const int cq = b & 3;
    const int nk = b >> 2;
    const int n  = nk >> 6, k = nk & 63;
    const int t  = threadIdx.x;

    for (int i = t; i < HW_; i += 256) sa_s[i] = sa[(size_t)nk * HW_ + i];
    __syncthreads();
    for (int p = t; p < P_; p += 256) {
        const int hp = p / WP_, wp = p - hp * WP_;
        float bs = 0.f;
#pragma unroll
        for (int dh = 0; dh < 4; ++dh) {
            const float* r = &sa_s[(hp + dh) * W_ + wp];
            bs += r[0] + r[1] + r[2] + r[3];
        }
        const float sc = inv1[(size_t)nk * P_ + p] * inv2[n * P_ + p];
        scl_s[p] = sc;
        t2_s[p]  = bs * sc;
    }

    const float* xb = xnT + (size_t)n * C_ * HW_;
    float* ob = outl + (size_t)nk * CP_;

    for (int g = 0; g < 8; ++g) {
        const int c0 = cq * 32 + g * 4;
        const float* x0 = xb + (size_t)(c0 + 0) * HW_;
        const float* x1 = xb + (size_t)(c0 + 1) * HW_;
        const float* x2 = xb + (size_t)(c0 + 2) * HW_;
        const float* x3 = xb + (size_t)(c0 + 3) * HW_;
        __syncthreads();   // prior group's cs_q readers done; scl/t2 visible (g=0)
        COLSUM_VEC_T(cs_q, sa_s, x0, x1, x2, x3)
        __syncthreads();
        const float4 ce = ld4(&cent[k * C_ + c0]);
#pragma unroll
        for (int pi = 0; pi < 4; ++pi) {
            const int p = t + pi * 256;
            if (p < P_) {
                const int hp = p / WP_, wp = p - hp * WP_;
                const int base = hp * W_ + wp;
                const float4 s0 = csget(cs_q, base);
                const float4 s1 = csget(cs_q, base + 1);
                const float4 s2 = csget(cs_q, base + 2);
                const float4 s3 = csget(cs_q, base + 3);
                const float sc = scl_s[p];
                const float tt = t2_s[p];
                ob[(size_t)(c0 + 0) * P_ + p] = (s0.x + s1.x + s2.x + s3.x) * sc - ce.x * tt;
                ob[(size_t)(c0 + 1) * P_ + p] = (s0.y + s1.y + s2.y + s3.y) * sc - ce.y * tt;
                ob[(size_t)(c0 + 2) * P_ + p] = (s0.z + s1.z + s2.z + s3.z) * sc - ce.z * tt;
                ob[(size_t)(c0 + 3) * P_ + p] = (s0.w + s1.w + s2.w + s3.w) * sc - ce.w * tt;
            }
        }
    }
}

// ---------------------------------------------------------------------------
extern "C" void kernel_launch(void* const* d_in, const int* in_sizes, int n_in,
                              void* d_out, int out_size, void* d_ws, size_t ws_size,
                              hipStream_t stream)
{
    const float* x      = (const float*)d_in[0];
    const float* conv_w = (const float*)d_in[1];
    const float* cent   = (const float*)d_in[2];
    float* out = (float*)d_out;
    float* ws  = (float*)d_ws;

    // workspace layout (floats)
    float* xnT  = ws;                       // 614400
    float* xnP  = ws + 614400;              // 614400
    float* sa   = ws + 1228800;             // 307200
    float* vg_u = ws + 1536000;             // 32768
    float* vg_r = ws + 1568768;             // 256
    float* nsqp = ws + 1569024;             // 1022976
    float* inv1 = ws + 2592000;             // 255744
    float* rloc = ws + 2847744;             // 255744
    float* inv2 = ws + 3103488;             // 3996

    float* outl = out + (size_t)N_ * KC_;   // output 1 region

    k1_norm_softmax<<<N_ * H_, 256, 0, stream>>>(x, conv_w, xnT, xnP, sa);
    k2_vg<<<N_ * K_, 1024, 0, stream>>>(sa, xnP, cent, vg_u, vg_r);
    k3_vg_fin<<<N_, 256, 0, stream>>>(vg_u, vg_r, out);
    k4_norm<<<N_ * K_ * 4, 256, 0, stream>>>(sa, xnT, cent, nsqp);
    k5_combine<<<N_ * K_, 256, 0, stream>>>(nsqp, inv1, rloc);
    k6_inv2<<<N_ * 4, 256, 0, stream>>>(rloc, inv2);
    k7_write<<<N_ * K_ * 4, 256, 0, stream>>>(sa, xnT, cent, inv1, inv2, outl);
}

// Round 6
// 123.051 us; speedup vs baseline: 1.5257x; 1.0249x over previous
//
#include <hip/hip_runtime.h>
#include <math.h>

#define EPSV 1e-12f

namespace {
constexpr int N_  = 4;
constexpr int C_  = 128;
constexpr int H_  = 30;
constexpr int W_  = 40;
constexpr int K_  = 64;
constexpr int HW_ = H_ * W_;        // 1200
constexpr int HP_ = 27;             // H+1-4
constexpr int WP_ = 37;             // W+1-4
constexpr int P_  = HP_ * WP_;      // 999
constexpr int KC_ = K_ * C_;        // 8192
constexpr int CP_ = C_ * P_;        // 127872 floats per (n,k) slab
constexpr int CS_ = HP_ * W_;       // 1080 colsum rows
constexpr int SL_ = CS_ / 4;        // 270 vector slots (270*4 ≡ 24 mod 32: q-rows
                                    // land on distinct banks — do NOT pad to 272)
}

static __device__ __forceinline__ float4 ld4(const float* p) {
    return *reinterpret_cast<const float4*>(p);
}

// ---------------------------------------------------------------------------
// K1: per (n,h) row — L2-normalize x over channels, write xn in two layouts,
//     compute conv scores + softmax -> sa  (layout [n][k][pix])
// ---------------------------------------------------------------------------
__global__ __launch_bounds__(256) void k1_norm_softmax(
    const float* __restrict__ x, const float* __restrict__ conv_w,
    float* __restrict__ xnT, float* __restrict__ xnP, float* __restrict__ sa)
{
    __shared__ float xrow[C_ * W_];   // [c][w]
    __shared__ float conv_s[K_ * C_]; // [k][c]
    __shared__ float invn[W_];
    __shared__ float s_s[K_ * W_];    // [k][w]

    const int b = blockIdx.x;         // n*H + h
    const int n = b / H_, h = b - n * H_;
    const int t = threadIdx.x;

    for (int i = t; i < C_ * W_; i += 256) {
        const int c = i / W_, w = i - c * W_;
        xrow[i] = x[(size_t)(n * C_ + c) * HW_ + h * W_ + w];
    }
    for (int i = t; i < K_ * C_; i += 256) conv_s[i] = conv_w[i];
    __syncthreads();

    if (t < W_) {
        float s = 0.f;
        for (int c = 0; c < C_; ++c) { const float v = xrow[c * W_ + t]; s += v * v; }
        invn[t] = 1.f / fmaxf(sqrtf(s), EPSV);
    }
    __syncthreads();

    for (int i = t; i < C_ * W_; i += 256) {
        const int c = i / W_, w = i - c * W_;
        const float v = xrow[i] * invn[w];
        xrow[i] = v;
        xnT[(size_t)(n * C_ + c) * HW_ + h * W_ + w] = v;
    }
    __syncthreads();

    for (int i = t; i < W_ * C_; i += 256) {
        const int w = i / C_, c = i - w * C_;
        xnP[((size_t)n * HW_ + h * W_ + w) * C_ + c] = xrow[c * W_ + w];
    }

    for (int d = t; d < K_ * W_; d += 256) {
        const int k = d / W_, w = d - k * W_;
        const float* cw = &conv_s[k * C_];
        float s = 0.f;
        for (int c = 0; c < C_; ++c) s += cw[c] * xrow[c * W_ + w];
        s_s[d] = s;
    }
    __syncthreads();

    if (t < W_) {
        const int w = t;
        float m = -1e30f;
        for (int k = 0; k < K_; ++k) m = fmaxf(m, s_s[k * W_ + w]);
        float sum = 0.f;
        for (int k = 0; k < K_; ++k) sum += expf(s_s[k * W_ + w] - m);
        const float inv = 1.f / sum;
        for (int k = 0; k < K_; ++k)
            sa[(size_t)(n * K_ + k) * HW_ + h * W_ + w] = expf(s_s[k * W_ + w] - m) * inv;
    }
}

// ---------------------------------------------------------------------------
// Vectorized fused colsum with TRANSPOSED output cs_q[q][s] (conflict-free
// writes; see Round-5 note).
// ---------------------------------------------------------------------------
#define COLSUM_VEC_T(cs_q, sa_s, x0, x1, x2, x3)                                \
    for (int s = t; s < SL_; s += 256) {                                        \
        const int i = s * 4;                                                    \
        const float4 sa0 = ld4(&sa_s[i]);                                       \
        const float4 sa1 = ld4(&sa_s[i + W_]);                                  \
        const float4 sa2 = ld4(&sa_s[i + 2 * W_]);                              \
        const float4 sa3 = ld4(&sa_s[i + 3 * W_]);                              \
        float acc[4][4];                                                        \
        const float* xc[4] = {x0, x1, x2, x3};                                  \
        _Pragma("unroll")                                                       \
        for (int ch = 0; ch < 4; ++ch) {                                        \
            const float4 a0 = ld4(xc[ch] + i);                                  \
            const float4 a1 = ld4(xc[ch] + i + W_);                             \
            const float4 a2 = ld4(xc[ch] + i + 2 * W_);                         \
            const float4 a3 = ld4(xc[ch] + i + 3 * W_);                         \
            acc[0][ch] = sa0.x * a0.x + sa1.x * a1.x + sa2.x * a2.x + sa3.x * a3.x; \
            acc[1][ch] = sa0.y * a0.y + sa1.y * a1.y + sa2.y * a2.y + sa3.y * a3.y; \
            acc[2][ch] = sa0.z * a0.z + sa1.z * a1.z + sa2.z * a2.z + sa3.z * a3.z; \
            acc[3][ch] = sa0.w * a0.w + sa1.w * a1.w + sa2.w * a2.w + sa3.w * a3.w; \
        }                                                                       \
        _Pragma("unroll")                                                       \
        for (int q = 0; q < 4; ++q)                                             \
            cs_q[q][s] = make_float4(acc[q][0], acc[q][1], acc[q][2], acc[q][3]); \
    }

// fetch colsum float4 (channels) for linear colsum pixel e
static __device__ __forceinline__ float4 csget(const float4 cs_q[4][SL_], int e) {
    return cs_q[e & 3][e >> 2];
}

// ---------------------------------------------------------------------------
// K4m: merged launch.
//   blocks [0,256):    vlad_global per (n,k) — latency-bound work hidden
//                      under the co-resident norm-pass blocks.
//   blocks [256,1280): NORM-ONLY box-sum pass (writes nsqp only).
// ---------------------------------------------------------------------------
__global__ __launch_bounds__(256) void k4_merged(
    const float* __restrict__ sa, const float* __restrict__ xnT,
    const float* __restrict__ xnP, const float* __restrict__ cent,
    float* __restrict__ nsqp, float* __restrict__ vg_u,
    float* __restrict__ vg_r)
{
    __shared__ float  sa_s[HW_];
    __shared__ float  B_s[P_];
    __shared__ float4 cs_q[4][SL_];
    __shared__ float  gs[256], bss[256];
    __shared__ float  red[2];

    const int t = threadIdx.x;

    if (blockIdx.x < 256) {
        // ---- vlad_global path (R3-verified 256-thread version) ----
        const int b = blockIdx.x;         // n*K + k
        const int n = b >> 6, k = b & 63;
        const int c = t & 127, half = t >> 7;
        constexpr int HHW = HW_ / 2;      // 600

        const float* sarow = &sa[(size_t)b * HW_ + half * HHW];
        const float* xp = &xnP[((size_t)n * HW_ + half * HHW) * C_ + c];
        float g0 = 0.f, g1 = 0.f, g2 = 0.f, g3 = 0.f;
        float b0 = 0.f, b1 = 0.f, b2 = 0.f, b3 = 0.f;
        for (int pix = 0; pix < HHW; pix += 4) {
            const float s0 = sarow[pix + 0], s1 = sarow[pix + 1];
            const float s2 = sarow[pix + 2], s3 = sarow[pix + 3];
            g0 += s0 * xp[(size_t)(pix + 0) * C_];
            g1 += s1 * xp[(size_t)(pix + 1) * C_];
            g2 += s2 * xp[(size_t)(pix + 2) * C_];
            g3 += s3 * xp[(size_t)(pix + 3) * C_];
            b0 += s0; b1 += s1; b2 += s2; b3 += s3;
        }
        gs[t]  = (g0 + g1) + (g2 + g3);
        bss[t] = (b0 + b1) + (b2 + b3);
        __syncthreads();

        float vg = 0.f;
        if (t < 128) {
            vg = (gs[t] + gs[t + 128]) - cent[k * C_ + c] * (bss[t] + bss[t + 128]);
            float nsq = vg * vg;
            for (int off = 32; off >= 1; off >>= 1) nsq += __shfl_down(nsq, off);
            if ((t & 63) == 0) red[t >> 6] = nsq;
        }
        __syncthreads();
        const float tot  = red[0] + red[1];
        const float norm = sqrtf(tot);
        const float iv   = 1.f / fmaxf(norm, EPSV);
        if (t < 128) vg_u[(size_t)b * C_ + t] = vg * iv;
        if (t == 0) { const float rr = norm * iv; vg_r[b] = rr * rr; }
        return;
    }

    // ---- norm-pass path ----
    const int b  = blockIdx.x - 256;      // ((n*K + k)*4 + cq)
    const int cq = b & 3;
    const int nk = b >> 2;
    const int n  = nk >> 6, k = nk & 63;

    for (int i = t; i < HW_; i += 256) sa_s[i] = sa[(size_t)nk * HW_ + i];
    __syncthreads();
    for (int p = t; p < P_; p += 256) {
        const int hp = p / WP_, wp = p - hp * WP_;
        float bs = 0.f;
#pragma unroll
        for (int dh = 0; dh < 4; ++dh) {
            const float* r = &sa_s[(hp + dh) * W_ + wp];
            bs += r[0] + r[1] + r[2] + r[3];
        }
        B_s[p] = bs;
    }

    float nsq0 = 0.f, nsq1 = 0.f, nsq2 = 0.f, nsq3 = 0.f;
    const float* xb = xnT + (size_t)n * C_ * HW_;

    for (int g = 0; g < 8; ++g) {
        const int c0 = cq * 32 + g * 4;
        const float* x0 = xb + (size_t)(c0 + 0) * HW_;
        const float* x1 = xb + (size_t)(c0 + 1) * HW_;
        const float* x2 = xb + (size_t)(c0 + 2) * HW_;
        const float* x3 = xb + (size_t)(c0 + 3) * HW_;
        __syncthreads();   // prior group's cs_q readers done; B_s visible (g=0)
        COLSUM_VEC_T(cs_q, sa_s, x0, x1, x2, x3)
        __syncthreads();
        const float4 ce = ld4(&cent[k * C_ + c0]);
#pragma unroll
        for (int pi = 0; pi < 4; ++pi) {
            const int p = t + pi * 256;
            if (p < P_) {
                const int hp = p / WP_, wp = p - hp * WP_;
                const int base = hp * W_ + wp;
                const float4 s0 = csget(cs_q, base);
                const float4 s1 = csget(cs_q, base + 1);
                const float4 s2 = csget(cs_q, base + 2);
                const float4 s3 = csget(cs_q, base + 3);
                const float Bv = B_s[p];
                const float ux = (s0.x + s1.x + s2.x + s3.x) - ce.x * Bv;
                const float uy = (s0.y + s1.y + s2.y + s3.y) - ce.y * Bv;
                const float uz = (s0.z + s1.z + s2.z + s3.z) - ce.z * Bv;
                const float uw = (s0.w + s1.w + s2.w + s3.w) - ce.w * Bv;
                const float add = ux * ux + uy * uy + uz * uz + uw * uw;
                if      (pi == 0) nsq0 += add;
                else if (pi == 1) nsq1 += add;
                else if (pi == 2) nsq2 += add;
                else              nsq3 += add;
            }
        }
    }
#pragma unroll
    for (int pi = 0; pi < 4; ++pi) {
        const int p = t + pi * 256;
        if (p < P_) {
            const float v = (pi == 0 ? nsq0 : pi == 1 ? nsq1 : pi == 2 ? nsq2 : nsq3);
            nsqp[(size_t)b * P_ + p] = v * 0.00390625f;  // (1/16)^2
        }
    }
}

// ---------------------------------------------------------------------------
// K5m: merged launch.
//   blocks [0,256):   combine 4 cq partials -> inv1 (×1/16 folded) + rloc.
//   blocks [256,260): vlad_global finalize (2nd L2 norm, writes output 0).
// ---------------------------------------------------------------------------
__global__ __launch_bounds__(256) void k5_merged(
    const float* __restrict__ nsqp, float* __restrict__ inv1,
    float* __restrict__ rloc, const float* __restrict__ vg_u,
    const float* __restrict__ vg_r, float* __restrict__ out)
{
    const int t = threadIdx.x;
    if (blockIdx.x >= 256) {
        const int n = blockIdx.x - 256;
        __shared__ float inv2s;
        if (t == 0) {
            float s = 0.f;
            for (int k = 0; k < K_; ++k) s += vg_r[n * K_ + k];
            inv2s = 1.f / fmaxf(sqrtf(s), EPSV);
        }
        __syncthreads();
        const float inv2 = inv2s;
        for (int i = t; i < KC_; i += 256)
            out[(size_t)n * KC_ + i] = vg_u[(size_t)n * KC_ + i] * inv2;
        return;
    }
    const int nk = blockIdx.x;
    for (int p = t; p < P_; p += 256) {
        const float s = nsqp[(size_t)(nk * 4 + 0) * P_ + p]
                      + nsqp[(size_t)(nk * 4 + 1) * P_ + p]
                      + nsqp[(size_t)(nk * 4 + 2) * P_ + p]
                      + nsqp[(size_t)(nk * 4 + 3) * P_ + p];
        const float norm = sqrtf(s);
        const float iv = 1.f / fmaxf(norm, EPSV);
        inv1[(size_t)nk * P_ + p] = iv * 0.0625f;   // fold 1/16
        const float rr = norm * iv;
        rloc[(size_t)nk * P_ + p] = rr * rr;
    }
}

// K6: inv2[n,p] = 1/max(sqrt(sum_k r),EPS)
__global__ __launch_bounds__(256) void k6_inv2(
    const float* __restrict__ rloc, float* __restrict__ inv2)
{
    const int n = blockIdx.x >> 2;
    const int p = (blockIdx.x & 3) * 256 + threadIdx.x;
    if (p < P_) {
        float s = 0.f;
        for (int k = 0; k < K_; ++k) s += rloc[(size_t)(n * K_ + k) * P_ + p];
        inv2[n * P_ + p] = 1.f / fmaxf(sqrtf(s), EPSV);
    }
}

// ---------------------------------------------------------------------------
// K7w: WRITE pass with float4 stores.
//   Channel bundles {c, c+4, c+8, c+12} (all ≡ m mod 4) so that row starts
//   share one misalignment class; vector slots start at p ≡ m (mod 4)
//   (999 ≡ −1 mod 4 ⇒ m·999 + m ≡ 0), giving aligned dwordx4 stores for
//   996/999 patches; 3 scalar stragglers per bundle.
// ---------------------------------------------------------------------------
__global__ __launch_bounds__(256) void k7_write(
    const float* __restrict__ sa, const float* __restrict__ xnT,
    const float* __restrict__ cent, const float* __restrict__ inv1,
    const float* __restrict__ inv2, float* __restrict__ outl)
{
    __shared__ float  sa_s[HW_];
    __shared__ float  scl_s[P_];
    __shared__ float  t2_s[P_];
    __shared__ float4 cs_q[4][SL_];

    const int b  = blockIdx.x;            // ((n*K + k)*4 + cq)
    const int cq = b & 3;
    const int nk = b >> 2;
    const int n  = nk >> 6, k = nk & 63;
    const int t  = threadIdx.x;

    for (int i = t; i < HW_; i += 256) sa_s[i] = sa[(size_t)nk * HW_ + i];
    __syncthreads();
    for (int p = t; p < P_; p += 256) {
        const int hp = p / WP_, wp = p - hp * WP_;
        float bs = 0.f;
#pragma unroll
        for (int dh = 0; dh < 4; ++dh) {
            const float* r = &sa_s[(hp + dh) * W_ + wp];
            bs += r[0] + r[1] + r[2] + r[3];
        }
        const float sc = inv1[(size_t)nk * P_ + p] * inv2[n * P_ + p];
        scl_s[p] = sc;
        t2_s[p]  = bs * sc;
    }

    const float* xb = xnT + (size_t)n * C_ * HW_;
    float* ob = outl + (size_t)nk * CP_;

    for (int g = 0; g < 8; ++g) {
        const int m = g & 3, h8 = g >> 2;
        const int c0 = cq * 32 + h8 * 16 + m;          // bundle: c0,c0+4,c0+8,c0+12
        const float* x0 = xb + (size_t)(c0 + 0) * HW_;
        const float* x1 = xb + (size_t)(c0 + 4) * HW_;
        const float* x2 = xb + (size_t)(c0 + 8) * HW_;
        const float* x3 = xb + (size_t)(c0 + 12) * HW_;
        __syncthreads();   // prior group's cs_q readers done; scl/t2 visible (g=0)
        COLSUM_VEC_T(cs_q, sa_s, x0, x1, x2, x3)
        __syncthreads();
        const float ce0 = cent[k * C_ + c0];
        const float ce1 = cent[k * C_ + c0 + 4];
        const float ce2 = cent[k * C_ + c0 + 8];
        const float ce3 = cent[k * C_ + c0 + 12];
        float* ob0 = ob + (size_t)(c0 + 0) * P_;
        float* ob1 = ob + (size_t)(c0 + 4) * P_;
        float* ob2 = ob + (size_t)(c0 + 8) * P_;
        float* ob3 = ob + (size_t)(c0 + 12) * P_;

        if (t < 249) {                                 // vector slots: p ∈ [m, m+996)
            const int p0 = m + t * 4;
            float4 v0, v1, v2, v3;
#pragma unroll
            for (int pi = 0; pi < 4; ++pi) {
                const int p = p0 + pi;
                const int hp = p / WP_, wp = p - hp * WP_;
                const int base = hp * W_ + wp;
                const float4 s0 = csget(cs_q, base);
                const float4 s1 = csget(cs_q, base + 1);
                const float4 s2 = csget(cs_q, base + 2);
                const float4 s3 = csget(cs_q, base + 3);
                const float sc = scl_s[p], tt = t2_s[p];
                reinterpret_cast<float*>(&v0)[pi] = (s0.x + s1.x + s2.x + s3.x) * sc - ce0 * tt;
                reinterpret_cast<float*>(&v1)[pi] = (s0.y + s1.y + s2.y + s3.y) * sc - ce1 * tt;
                reinterpret_cast<float*>(&v2)[pi] = (s0.z + s1.z + s2.z + s3.z) * sc - ce2 * tt;
                reinterpret_cast<float*>(&v3)[pi] = (s0.w + s1.w + s2.w + s3.w) * sc - ce3 * tt;
            }
            *reinterpret_cast<float4*>(ob0 + p0) = v0;
            *reinterpret_cast<float4*>(ob1 + p0) = v1;
            *reinterpret_cast<float4*>(ob2 + p0) = v2;
            *reinterpret_cast<float4*>(ob3 + p0) = v3;
        } else if (t < 252) {                          // 3 scalar stragglers
            const int u = t - 249;
            const int p = (u < m) ? u : 996 + u;       // {0..m-1} ∪ {m+996..998}
            const int hp = p / WP_, wp = p - hp * WP_;
            const int base = hp * W_ + wp;
            const float4 s0 = csget(cs_q, base);
            const float4 s1 = csget(cs_q, base + 1);
            const float4 s2 = csget(cs_q, base + 2);
            const float4 s3 = csget(cs_q, base + 3);
            const float sc = scl_s[p], tt = t2_s[p];
            ob0[p] = (s0.x + s1.x + s2.x + s3.x) * sc - ce0 * tt;
            ob1[p] = (s0.y + s1.y + s2.y + s3.y) * sc - ce1 * tt;
            ob2[p] = (s0.z + s1.z + s2.z + s3.z) * sc - ce2 * tt;
            ob3[p] = (s0.w + s1.w + s2.w + s3.w) * sc - ce3 * tt;
        }
    }
}

// ---------------------------------------------------------------------------
extern "C" void kernel_launch(void* const* d_in, const int* in_sizes, int n_in,
                              void* d_out, int out_size, void* d_ws, size_t ws_size,
                              hipStream_t stream)
{
    const float* x      = (const float*)d_in[0];
    const float* conv_w = (const float*)d_in[1];
    const float* cent   = (const float*)d_in[2];
    float* out = (float*)d_out;
    float* ws  = (float*)d_ws;

    // workspace layout (floats)
    float* xnT  = ws;                       // 614400
    float* xnP  = ws + 614400;              // 614400
    float* sa   = ws + 1228800;             // 307200
    float* vg_u = ws + 1536000;             // 32768
    float* vg_r = ws + 1568768;             // 256
    float* nsqp = ws + 1569024;             // 1022976
    float* inv1 = ws + 2592000;             // 255744
    float* rloc = ws + 2847744;             // 255744
    float* inv2 = ws + 3103488;             // 3996

    float* outl = out + (size_t)N_ * KC_;   // output 1 region

    k1_norm_softmax<<<N_ * H_, 256, 0, stream>>>(x, conv_w, xnT, xnP, sa);
    k4_merged<<<256 + N_ * K_ * 4, 256, 0, stream>>>(sa, xnT, xnP, cent,
                                                     nsqp, vg_u, vg_r);
    k5_merged<<<256 + N_, 256, 0, stream>>>(nsqp, inv1, rloc, vg_u, vg_r, out);
    k6_inv2<<<N_ * 4, 256, 0, stream>>>(rloc, inv2);
    k7_write<<<N_ * K_ * 4, 256, 0, stream>>>(sa, xnT, cent, inv1, inv2, outl);
}

// Round 7
// 120.189 us; speedup vs baseline: 1.5620x; 1.0238x over previous
//
#include <hip/hip_runtime.h>
#include <math.h>

#define EPSV 1e-12f

namespace {
constexpr int N_  = 4;
constexpr int C_  = 128;
constexpr int H_  = 30;
constexpr int W_  = 40;
constexpr int K_  = 64;
constexpr int HW_ = H_ * W_;        // 1200
constexpr int HP_ = 27;             // H+1-4
constexpr int WP_ = 37;             // W+1-4
constexpr int P_  = HP_ * WP_;      // 999
constexpr int PS_ = 1000;           // padded stride for p-indexed buffers
constexpr int KC_ = K_ * C_;        // 8192
constexpr int CP_ = C_ * P_;        // 127872 floats per (n,k) slab
constexpr int CS_ = HP_ * W_;       // 1080 colsum rows
constexpr int SL_ = CS_ / 4;        // 270 vector slots
constexpr int CVP_ = 132;           // padded row stride for conv_s / xrowT (132≡4 mod 32)
}

static __device__ __forceinline__ float4 ld4(const float* p) {
    return *reinterpret_cast<const float4*>(p);
}
static __device__ __forceinline__ float dot4(float4 a, float4 b) {
    return a.x * b.x + a.y * b.y + a.z * b.z + a.w * b.w;
}
static __device__ __forceinline__ float4 f4add(float4 a, float4 b) {
    return make_float4(a.x + b.x, a.y + b.y, a.z + b.z, a.w + b.w);
}

// ---------------------------------------------------------------------------
// K1: per (n,h) row — L2-normalize x, write xn two layouts, conv+softmax.
//     Score stage: xrowT (w-major, padded) + conv chunks in registers →
//     b128 LDS reads instead of stride-40 scalar reads.
// ---------------------------------------------------------------------------
__global__ __launch_bounds__(256) void k1_norm_softmax(
    const float* __restrict__ x, const float* __restrict__ conv_w,
    float* __restrict__ xnT, float* __restrict__ xnP, float* __restrict__ sa)
{
    __shared__ float xrow[C_ * W_];       // [c][w]
    __shared__ float conv_s[K_ * CVP_];   // [k][132]
    __shared__ float xrowT[W_ * CVP_];    // [w][132]
    __shared__ float invn[W_];
    __shared__ float s_s[K_ * W_];        // [k][w]

    const int b = blockIdx.x;             // n*H + h
    const int n = b / H_, h = b - n * H_;
    const int t = threadIdx.x;

    for (int i = t; i < C_ * W_; i += 256) {
        const int c = i / W_, w = i - c * W_;
        xrow[i] = x[(size_t)(n * C_ + c) * HW_ + h * W_ + w];
    }
    for (int i = t; i < K_ * C_; i += 256) {
        const int k = i >> 7, c = i & 127;
        conv_s[k * CVP_ + c] = conv_w[i];
    }
    __syncthreads();

    if (t < W_) {
        float s = 0.f;
        for (int c = 0; c < C_; ++c) { const float v = xrow[c * W_ + t]; s += v * v; }
        invn[t] = 1.f / fmaxf(sqrtf(s), EPSV);
    }
    __syncthreads();

    for (int i = t; i < C_ * W_; i += 256) {
        const int c = i / W_, w = i - c * W_;
        const float v = xrow[i] * invn[w];
        xrow[i] = v;
        xnT[(size_t)(n * C_ + c) * HW_ + h * W_ + w] = v;
    }
    __syncthreads();

    for (int i = t; i < W_ * C_; i += 256) {
        const int w = i / C_, c = i - w * C_;
        const float v = xrow[c * W_ + w];
        xnP[((size_t)n * HW_ + h * W_ + w) * C_ + c] = v;
        xrowT[w * CVP_ + c] = v;
    }
    __syncthreads();

    // scores: thread = (k, w-decile); conv chunk (8 float4) in registers
    {
        const int k = t >> 2, q = t & 3;
        float acc0 = 0.f, acc1 = 0.f, acc2 = 0.f, acc3 = 0.f, acc4 = 0.f;
        float acc5 = 0.f, acc6 = 0.f, acc7 = 0.f, acc8 = 0.f, acc9 = 0.f;
        const float* convk = &conv_s[k * CVP_];
        for (int ch = 0; ch < 4; ++ch) {
            float4 cv0 = ld4(convk + ch * 32 + 0),  cv1 = ld4(convk + ch * 32 + 4);
            float4 cv2 = ld4(convk + ch * 32 + 8),  cv3 = ld4(convk + ch * 32 + 12);
            float4 cv4 = ld4(convk + ch * 32 + 16), cv5 = ld4(convk + ch * 32 + 20);
            float4 cv6 = ld4(convk + ch * 32 + 24), cv7 = ld4(convk + ch * 32 + 28);
#pragma unroll
            for (int wi = 0; wi < 10; ++wi) {
                const float* xw = &xrowT[(q * 10 + wi) * CVP_ + ch * 32];
                float s = dot4(cv0, ld4(xw)) + dot4(cv1, ld4(xw + 4))
                        + dot4(cv2, ld4(xw + 8)) + dot4(cv3, ld4(xw + 12))
                        + dot4(cv4, ld4(xw + 16)) + dot4(cv5, ld4(xw + 20))
                        + dot4(cv6, ld4(xw + 24)) + dot4(cv7, ld4(xw + 28));
                if      (wi == 0) acc0 += s; else if (wi == 1) acc1 += s;
                else if (wi == 2) acc2 += s; else if (wi == 3) acc3 += s;
                else if (wi == 4) acc4 += s; else if (wi == 5) acc5 += s;
                else if (wi == 6) acc6 += s; else if (wi == 7) acc7 += s;
                else if (wi == 8) acc8 += s; else              acc9 += s;
            }
        }
        float* sd = &s_s[k * W_ + q * 10];
        sd[0] = acc0; sd[1] = acc1; sd[2] = acc2; sd[3] = acc3; sd[4] = acc4;
        sd[5] = acc5; sd[6] = acc6; sd[7] = acc7; sd[8] = acc8; sd[9] = acc9;
    }
    __syncthreads();

    if (t < W_) {
        const int w = t;
        float m = -1e30f;
        for (int k = 0; k < K_; ++k) m = fmaxf(m, s_s[k * W_ + w]);
        float sum = 0.f;
        for (int k = 0; k < K_; ++k) sum += expf(s_s[k * W_ + w] - m);
        const float inv = 1.f / sum;
        for (int k = 0; k < K_; ++k)
            sa[(size_t)(n * K_ + k) * HW_ + h * W_ + w] = expf(s_s[k * W_ + w] - m) * inv;
    }
}

// ---------------------------------------------------------------------------
// Vectorized fused colsum, transposed cs_q[q][s] (conflict-free writes).
// ---------------------------------------------------------------------------
#define COLSUM_VEC_T(cs_q, sa_s, x0, x1, x2, x3)                                \
    for (int s = t; s < SL_; s += 256) {                                        \
        const int i = s * 4;                                                    \
        const float4 sa0 = ld4(&sa_s[i]);                                       \
        const float4 sa1 = ld4(&sa_s[i + W_]);                                  \
        const float4 sa2 = ld4(&sa_s[i + 2 * W_]);                              \
        const float4 sa3 = ld4(&sa_s[i + 3 * W_]);                              \
        float acc[4][4];                                                        \
        const float* xc[4] = {x0, x1, x2, x3};                                  \
        _Pragma("unroll")                                                       \
        for (int ch = 0; ch < 4; ++ch) {                                        \
            const float4 a0 = ld4(xc[ch] + i);                                  \
            const float4 a1 = ld4(xc[ch] + i + W_);                             \
            const float4 a2 = ld4(xc[ch] + i + 2 * W_);                         \
            const float4 a3 = ld4(xc[ch] + i + 3 * W_);                         \
            acc[0][ch] = sa0.x * a0.x + sa1.x * a1.x + sa2.x * a2.x + sa3.x * a3.x; \
            acc[1][ch] = sa0.y * a0.y + sa1.y * a1.y + sa2.y * a2.y + sa3.y * a3.y; \
            acc[2][ch] = sa0.z * a0.z + sa1.z * a1.z + sa2.z * a2.z + sa3.z * a3.z; \
            acc[3][ch] = sa0.w * a0.w + sa1.w * a1.w + sa2.w * a2.w + sa3.w * a3.w; \
        }                                                                       \
        _Pragma("unroll")                                                       \
        for (int q = 0; q < 4; ++q)                                             \
            cs_q[q][s] = make_float4(acc[q][0], acc[q][1], acc[q][2], acc[q][3]); \
    }

// 10-value window read: v_j = cs[b0+j]; pairs t_j = v_j+v_{j+1}; windows
// w_j = t_j+t_{j+2}; window(pi) = pi<d ? w[pi] : w[pi+3]  (row crossing = +3
// shift in linear e-space). Emits A0..A3 float4 (channels) for p0..p0+3.
#define WINDOW10(cs_q, b0, d, A0, A1, A2, A3)                                   \
    {                                                                           \
        float4 v0 = cs_q[(b0 + 0) & 3][(b0 + 0) >> 2];                          \
        float4 v1 = cs_q[(b0 + 1) & 3][(b0 + 1) >> 2];                          \
        float4 v2 = cs_q[(b0 + 2) & 3][(b0 + 2) >> 2];                          \
        float4 v3 = cs_q[(b0 + 3) & 3][(b0 + 3) >> 2];                          \
        float4 v4 = cs_q[(b0 + 4) & 3][(b0 + 4) >> 2];                          \
        float4 v5 = cs_q[(b0 + 5) & 3][(b0 + 5) >> 2];                          \
        float4 v6 = cs_q[(b0 + 6) & 3][(b0 + 6) >> 2];                          \
        float4 v7 = cs_q[(b0 + 7) & 3][(b0 + 7) >> 2];                          \
        float4 v8 = cs_q[(b0 + 8) & 3][(b0 + 8) >> 2];                          \
        float4 v9 = cs_q[(b0 + 9) & 3][(b0 + 9) >> 2];                          \
        const float4 t0 = f4add(v0, v1), t1 = f4add(v1, v2), t2 = f4add(v2, v3);\
        const float4 t3 = f4add(v3, v4), t4 = f4add(v4, v5), t5 = f4add(v5, v6);\
        const float4 t6 = f4add(v6, v7), t7 = f4add(v7, v8), t8 = f4add(v8, v9);\
        const float4 w0 = f4add(t0, t2), w1 = f4add(t1, t3), w2 = f4add(t2, t4);\
        const float4 w3 = f4add(t3, t5), w4 = f4add(t4, t6), w5 = f4add(t5, t7);\
        const float4 w6 = f4add(t6, t8);                                        \
        A0 = (0 < d) ? w0 : w3;                                                 \
        A1 = (1 < d) ? w1 : w4;                                                 \
        A2 = (2 < d) ? w2 : w5;                                                 \
        A3 = (3 < d) ? w3 : w6;                                                 \
    }

// ---------------------------------------------------------------------------
// K4m: merged launch. blocks[0,256): vlad_global; blocks[256,1280): norm pass.
//      Norm pass: p-quads per thread, B + nsq fully in registers.
// ---------------------------------------------------------------------------
__global__ __launch_bounds__(256) void k4_merged(
    const float* __restrict__ sa, const float* __restrict__ xnT,
    const float* __restrict__ xnP, const float* __restrict__ cent,
    float* __restrict__ nsqp, float* __restrict__ vg_u,
    float* __restrict__ vg_r)
{
    __shared__ float  sa_s[HW_ + 8];      // +8: uniform window reads may run past
    __shared__ float4 cs_q[4][SL_ + 1];   // +1 slot: reads up to e=1083
    __shared__ float  gs[256], bss[256];
    __shared__ float  red[2];

    const int t = threadIdx.x;

    if (blockIdx.x < 256) {
        const int b = blockIdx.x;         // n*K + k
        const int n = b >> 6, k = b & 63;
        const int c = t & 127, half = t >> 7;
        constexpr int HHW = HW_ / 2;      // 600

        const float* sarow = &sa[(size_t)b * HW_ + half * HHW];
        const float* xp = &xnP[((size_t)n * HW_ + half * HHW) * C_ + c];
        float g0 = 0.f, g1 = 0.f, g2 = 0.f, g3 = 0.f;
        float b0 = 0.f, b1 = 0.f, b2 = 0.f, b3 = 0.f;
        for (int pix = 0; pix < HHW; pix += 4) {
            const float s0 = sarow[pix + 0], s1 = sarow[pix + 1];
            const float s2 = sarow[pix + 2], s3 = sarow[pix + 3];
            g0 += s0 * xp[(size_t)(pix + 0) * C_];
            g1 += s1 * xp[(size_t)(pix + 1) * C_];
            g2 += s2 * xp[(size_t)(pix + 2) * C_];
            g3 += s3 * xp[(size_t)(pix + 3) * C_];
            b0 += s0; b1 += s1; b2 += s2; b3 += s3;
        }
        gs[t]  = (g0 + g1) + (g2 + g3);
        bss[t] = (b0 + b1) + (b2 + b3);
        __syncthreads();

        float vg = 0.f;
        if (t < 128) {
            vg = (gs[t] + gs[t + 128]) - cent[k * C_ + c] * (bss[t] + bss[t + 128]);
            float nsq = vg * vg;
            for (int off = 32; off >= 1; off >>= 1) nsq += __shfl_down(nsq, off);
            if ((t & 63) == 0) red[t >> 6] = nsq;
        }
        __syncthreads();
        const float tot  = red[0] + red[1];
        const float norm = sqrtf(tot);
        const float iv   = 1.f / fmaxf(norm, EPSV);
        if (t < 128) vg_u[(size_t)b * C_ + t] = vg * iv;
        if (t == 0) { const float rr = norm * iv; vg_r[b] = rr * rr; }
        return;
    }

    const int b  = blockIdx.x - 256;      // ((n*K + k)*4 + cq)
    const int cq = b & 3;
    const int nk = b >> 2;
    const int n  = nk >> 6, k = nk & 63;

    for (int i = t; i < HW_; i += 256) sa_s[i] = sa[(size_t)nk * HW_ + i];
    __syncthreads();

    // quad setup + B in registers (thread t < 250 owns p0 = 4t..4t+3)
    int hp0 = 0, b0 = 0, d = 4;
    float B0 = 0.f, B1 = 0.f, B2 = 0.f, B3 = 0.f;
    if (t < 250) {
        const int p0 = 4 * t;
        hp0 = p0 / WP_;
        const int wp0 = p0 - hp0 * WP_;
        b0 = p0 + 3 * hp0;
        d  = WP_ - wp0;
        const float* r0 = &sa_s[hp0 * W_ + wp0];
        float sc[10];
#pragma unroll
        for (int j = 0; j < 10; ++j)
            sc[j] = r0[j] + r0[j + W_] + r0[j + 2 * W_] + r0[j + 3 * W_];
        const float u0 = sc[0] + sc[1], u1 = sc[1] + sc[2], u2 = sc[2] + sc[3];
        const float u3 = sc[3] + sc[4], u4 = sc[4] + sc[5], u5 = sc[5] + sc[6];
        const float u6 = sc[6] + sc[7], u7 = sc[7] + sc[8], u8 = sc[8] + sc[9];
        const float wB0 = u0 + u2, wB1 = u1 + u3, wB2 = u2 + u4;
        const float wB3 = u3 + u5, wB4 = u4 + u6, wB5 = u5 + u7, wB6 = u6 + u8;
        B0 = (0 < d) ? wB0 : wB3;
        B1 = (1 < d) ? wB1 : wB4;
        B2 = (2 < d) ? wB2 : wB5;
        B3 = (3 < d) ? wB3 : wB6;
    }

    float4 nv0 = make_float4(0, 0, 0, 0), nv1 = nv0, nv2 = nv0, nv3 = nv0;
    const float* xb = xnT + (size_t)n * C_ * HW_;

    for (int g = 0; g < 8; ++g) {
        const int c0 = cq * 32 + g * 4;
        const float* x0 = xb + (size_t)(c0 + 0) * HW_;
        const float* x1 = xb + (size_t)(c0 + 1) * HW_;
        const float* x2 = xb + (size_t)(c0 + 2) * HW_;
        const float* x3 = xb + (size_t)(c0 + 3) * HW_;
        __syncthreads();   // prior group's cs_q readers done
        COLSUM_VEC_T(cs_q, sa_s, x0, x1, x2, x3)
        __syncthreads();
        if (t < 250) {
            const float4 ce = ld4(&cent[k * C_ + c0]);
            float4 A0, A1, A2, A3;
            WINDOW10(cs_q, b0, d, A0, A1, A2, A3)
            const float4 e0 = make_float4(A0.x - ce.x * B0, A0.y - ce.y * B0,
                                          A0.z - ce.z * B0, A0.w - ce.w * B0);
            const float4 e1 = make_float4(A1.x - ce.x * B1, A1.y - ce.y * B1,
                                          A1.z - ce.z * B1, A1.w - ce.w * B1);
            const float4 e2 = make_float4(A2.x - ce.x * B2, A2.y - ce.y * B2,
                                          A2.z - ce.z * B2, A2.w - ce.w * B2);
            const float4 e3 = make_float4(A3.x - ce.x * B3, A3.y - ce.y * B3,
                                          A3.z - ce.z * B3, A3.w - ce.w * B3);
            nv0 = make_float4(nv0.x + e0.x * e0.x, nv0.y + e0.y * e0.y,
                              nv0.z + e0.z * e0.z, nv0.w + e0.w * e0.w);
            nv1 = make_float4(nv1.x + e1.x * e1.x, nv1.y + e1.y * e1.y,
                              nv1.z + e1.z * e1.z, nv1.w + e1.w * e1.w);
            nv2 = make_float4(nv2.x + e2.x * e2.x, nv2.y + e2.y * e2.y,
                              nv2.z + e2.z * e2.z, nv2.w + e2.w * e2.w);
            nv3 = make_float4(nv3.x + e3.x * e3.x, nv3.y + e3.y * e3.y,
                              nv3.z + e3.z * e3.z, nv3.w + e3.w * e3.w);
        }
    }
    if (t < 250) {
        const float s0 = (nv0.x + nv0.y) + (nv0.z + nv0.w);
        const float s1 = (nv1.x + nv1.y) + (nv1.z + nv1.w);
        const float s2 = (nv2.x + nv2.y) + (nv2.z + nv2.w);
        const float s3 = (nv3.x + nv3.y) + (nv3.z + nv3.w);
        *reinterpret_cast<float4*>(&nsqp[(size_t)b * PS_ + 4 * t]) =
            make_float4(s0 * 0.00390625f, s1 * 0.00390625f,
                        s2 * 0.00390625f, s3 * 0.00390625f);
    }
}

// ---------------------------------------------------------------------------
// K5m: blocks[0,256): combine cq partials (float4 quads); [256,260): vg fin.
// ---------------------------------------------------------------------------
__global__ __launch_bounds__(256) void k5_merged(
    const float* __restrict__ nsqp, float* __restrict__ inv1,
    float* __restrict__ rloc, const float* __restrict__ vg_u,
    const float* __restrict__ vg_r, float* __restrict__ out)
{
    const int t = threadIdx.x;
    if (blockIdx.x >= 256) {
        const int n = blockIdx.x - 256;
        __shared__ float inv2s;
        if (t == 0) {
            float s = 0.f;
            for (int k = 0; k < K_; ++k) s += vg_r[n * K_ + k];
            inv2s = 1.f / fmaxf(sqrtf(s), EPSV);
        }
        __syncthreads();
        const float inv2 = inv2s;
        for (int i = t; i < KC_; i += 256)
            out[(size_t)n * KC_ + i] = vg_u[(size_t)n * KC_ + i] * inv2;
        return;
    }
    const int nk = blockIdx.x;
    if (t < 250) {
        const int p0 = 4 * t;
        const float4 a = ld4(&nsqp[(size_t)(nk * 4 + 0) * PS_ + p0]);
        const float4 b = ld4(&nsqp[(size_t)(nk * 4 + 1) * PS_ + p0]);
        const float4 c = ld4(&nsqp[(size_t)(nk * 4 + 2) * PS_ + p0]);
        const float4 e = ld4(&nsqp[(size_t)(nk * 4 + 3) * PS_ + p0]);
        float4 iv, rr;
#pragma unroll
        for (int j = 0; j < 4; ++j) {
            const float s = reinterpret_cast<const float*>(&a)[j]
                          + reinterpret_cast<const float*>(&b)[j]
                          + reinterpret_cast<const float*>(&c)[j]
                          + reinterpret_cast<const float*>(&e)[j];
            const float norm = sqrtf(s);
            const float v = 1.f / fmaxf(norm, EPSV);
            reinterpret_cast<float*>(&iv)[j] = v * 0.0625f;   // fold 1/16
            const float r = norm * v;
            reinterpret_cast<float*>(&rr)[j] = r * r;
        }
        *reinterpret_cast<float4*>(&inv1[(size_t)nk * PS_ + p0]) = iv;
        *reinterpret_cast<float4*>(&rloc[(size_t)nk * PS_ + p0]) = rr;
    }
}

// K6: inv2[n,p] = 1/max(sqrt(sum_k rloc),EPS) — float4 quads.
__global__ __launch_bounds__(256) void k6_inv2(
    const float* __restrict__ rloc, float* __restrict__ inv2)
{
    const int n = blockIdx.x;
    const int t = threadIdx.x;
    if (t < 250) {
        const int p0 = 4 * t;
        float4 s = make_float4(0, 0, 0, 0);
        for (int k = 0; k < K_; ++k) {
            const float4 r = ld4(&rloc[(size_t)(n * K_ + k) * PS_ + p0]);
            s = f4add(s, r);
        }
        float4 o;
        o.x = 1.f / fmaxf(sqrtf(s.x), EPSV);
        o.y = 1.f / fmaxf(sqrtf(s.y), EPSV);
        o.z = 1.f / fmaxf(sqrtf(s.z), EPSV);
        o.w = 1.f / fmaxf(sqrtf(s.w), EPSV);
        *reinterpret_cast<float4*>(&inv2[n * PS_ + p0]) = o;
    }
}

// ---------------------------------------------------------------------------
// K7w: WRITE pass — 10-read windows + aligned float4 stores (m-offset scheme).
// ---------------------------------------------------------------------------
__global__ __launch_bounds__(256) void k7_write(
    const float* __restrict__ sa, const float* __restrict__ xnT,
    const float* __restrict__ cent, const float* __restrict__ inv1,
    const float* __restrict__ inv2, float* __restrict__ outl)
{
    __shared__ float  sa_s[HW_ + 8];
    __shared__ float  scl_s[P_];
    __shared__ float  t2_s[P_];
    __shared__ float4 cs_q[4][SL_ + 1];

    const int b  = blockIdx.x;            // ((n*K + k)*4 + cq)
    const int cq = b & 3;
    const int nk = b >> 2;
    const int n  = nk >> 6, k = nk & 63;
    const int t  = threadIdx.x;

    for (int i = t; i < HW_; i += 256) sa_s[i] = sa[(size_t)nk * HW_ + i];
    __syncthreads();
    for (int p = t; p < P_; p += 256) {
        const int hp = p / WP_, wp = p - hp * WP_;
        float bs = 0.f;
#pragma unroll
        for (int dh = 0; dh < 4; ++dh) {
            const float* r = &sa_s[(hp + dh) * W_ + wp];
            bs += r[0] + r[1] + r[2] + r[3];
        }
        const float sc = inv1[(size_t)nk * PS_ + p] * inv2[n * PS_ + p];
        scl_s[p] = sc;
        t2_s[p]  = bs * sc;
    }

    const float* xb = xnT + (size_t)n * C_ * HW_;
    float* ob = outl + (size_t)nk * CP_;

    for (int g = 0; g < 8; ++g) {
        const int m = g & 3, h8 = g >> 2;
        const int c0 = cq * 32 + h8 * 16 + m;          // bundle c0,c0+4,c0+8,c0+12
        const float* x0 = xb + (size_t)(c0 + 0) * HW_;
        const float* x1 = xb + (size_t)(c0 + 4) * HW_;
        const float* x2 = xb + (size_t)(c0 + 8) * HW_;
        const float* x3 = xb + (size_t)(c0 + 12) * HW_;
        __syncthreads();
        COLSUM_VEC_T(cs_q, sa_s, x0, x1, x2, x3)
        __syncthreads();
        const float ce0 = cent[k * C_ + c0];
        const float ce1 = cent[k * C_ + c0 + 4];
        const float ce2 = cent[k * C_ + c0 + 8];
        const float ce3 = cent[k * C_ + c0 + 12];
        float* ob0 = ob + (size_t)(c0 + 0) * P_;
        float* ob1 = ob + (size_t)(c0 + 4) * P_;
        float* ob2 = ob + (size_t)(c0 + 8) * P_;
        float* ob3 = ob + (size_t)(c0 + 12) * P_;

        if (t < 249) {                                 // vector: p ∈ [m, m+996)
            const int p0 = m + 4 * t;
            const int hp0 = p0 / WP_;
            const int wp0 = p0 - hp0 * WP_;
            const int b0 = p0 + 3 * hp0;
            const int d  = WP_ - wp0;
            const float sc0 = scl_s[p0 + 0], sc1 = scl_s[p0 + 1];
            const float sc2 = scl_s[p0 + 2], sc3 = scl_s[p0 + 3];
            const float tt0 = t2_s[p0 + 0], tt1 = t2_s[p0 + 1];
            const float tt2 = t2_s[p0 + 2], tt3 = t2_s[p0 + 3];
            float4 A0, A1, A2, A3;
            WINDOW10(cs_q, b0, d, A0, A1, A2, A3)
            const float4 s0v = make_float4(A0.x * sc0 - ce0 * tt0, A1.x * sc1 - ce0 * tt1,
                                           A2.x * sc2 - ce0 * tt2, A3.x * sc3 - ce0 * tt3);
            const float4 s1v = make_float4(A0.y * sc0 - ce1 * tt0, A1.y * sc1 - ce1 * tt1,
                                           A2.y * sc2 - ce1 * tt2, A3.y * sc3 - ce1 * tt3);
            const float4 s2v = make_float4(A0.z * sc0 - ce2 * tt0, A1.z * sc1 - ce2 * tt1,
                                           A2.z * sc2 - ce2 * tt2, A3.z * sc3 - ce2 * tt3);
            const float4 s3v = make_float4(A0.w * sc0 - ce3 * tt0, A1.w * sc1 - ce3 * tt1,
                                           A2.w * sc2 - ce3 * tt2, A3.w * sc3 - ce3 * tt3);
            *reinterpret_cast<float4*>(ob0 + p0) = s0v;
            *reinterpret_cast<float4*>(ob1 + p0) = s1v;
            *reinterpret_cast<float4*>(ob2 + p0) = s2v;
            *reinterpret_cast<float4*>(ob3 + p0) = s3v;
        } else if (t < 252) {                          // 3 scalar stragglers
            const int u = t - 249;
            const int p = (u < m) ? u : 996 + u;       // {0..m-1} ∪ {m+996..998}
            const int hp = p / WP_, wp = p - hp * WP_;
            const int base = hp * W_ + wp;
            const float4 s0 = cs_q[(base + 0) & 3][(base + 0) >> 2];
            const float4 s1 = cs_q[(base + 1) & 3][(base + 1) >> 2];
            const float4 s2 = cs_q[(base + 2) & 3][(base + 2) >> 2];
            const float4 s3 = cs_q[(base + 3) & 3][(base + 3) >> 2];
            const float sc = scl_s[p], tt = t2_s[p];
            ob0[p] = (s0.x + s1.x + s2.x + s3.x) * sc - ce0 * tt;
            ob1[p] = (s0.y + s1.y + s2.y + s3.y) * sc - ce1 * tt;
            ob2[p] = (s0.z + s1.z + s2.z + s3.z) * sc - ce2 * tt;
            ob3[p] = (s0.w + s1.w + s2.w + s3.w) * sc - ce3 * tt;
        }
    }
}

// ---------------------------------------------------------------------------
extern "C" void kernel_launch(void* const* d_in, const int* in_sizes, int n_in,
                              void* d_out, int out_size, void* d_ws, size_t ws_size,
                              hipStream_t stream)
{
    const float* x      = (const float*)d_in[0];
    const float* conv_w = (const float*)d_in[1];
    const float* cent   = (const float*)d_in[2];
    float* out = (float*)d_out;
    float* ws  = (float*)d_ws;

    // workspace layout (floats); p-indexed buffers use padded stride 1000
    float* xnT  = ws;                       // 614400
    float* xnP  = ws + 614400;              // 614400
    float* sa   = ws + 1228800;             // 307200
    float* vg_u = ws + 1536000;             // 32768
    float* vg_r = ws + 1568768;             // 256
    float* nsqp = ws + 1569024;             // 1024*1000 = 1024000
    float* inv1 = ws + 2593024;             // 256*1000  = 256000
    float* rloc = ws + 2849024;             // 256*1000  = 256000
    float* inv2 = ws + 3105024;             // 4*1000    = 4000  (total 12.44 MB)

    float* outl = out + (size_t)N_ * KC_;   // output 1 region

    k1_norm_softmax<<<N_ * H_, 256, 0, stream>>>(x, conv_w, xnT, xnP, sa);
    k4_merged<<<256 + N_ * K_ * 4, 256, 0, stream>>>(sa, xnT, xnP, cent,
                                                     nsqp, vg_u, vg_r);
    k5_merged<<<256 + N_, 256, 0, stream>>>(nsqp, inv1, rloc, vg_u, vg_r, out);
    k6_inv2<<<N_, 256, 0, stream>>>(rloc, inv2);
    k7_write<<<N_ * K_ * 4, 256, 0, stream>>>(sa, xnT, cent, inv1, inv2, outl);
}

// Round 8
// 118.943 us; speedup vs baseline: 1.5784x; 1.0105x over previous
//
#include <hip/hip_runtime.h>
#include <math.h>

#define EPSV 1e-12f

namespace {
constexpr int N_  = 4;
constexpr int C_  = 128;
constexpr int H_  = 30;
constexpr int W_  = 40;
constexpr int K_  = 64;
constexpr int HW_ = H_ * W_;        // 1200
constexpr int HP_ = 27;             // H+1-4
constexpr int WP_ = 37;             // W+1-4
constexpr int P_  = HP_ * WP_;      // 999
constexpr int PS_ = 1000;           // padded stride for p-indexed buffers
constexpr int KC_ = K_ * C_;        // 8192
constexpr int CP_ = C_ * P_;        // 127872 floats per (n,k) slab
constexpr int CS_ = HP_ * W_;       // 1080 colsum rows
constexpr int SL_ = CS_ / 4;        // 270 vector slots
constexpr int CVP_ = 132;           // padded row stride for conv_s / xrowT
}

static __device__ __forceinline__ float4 ld4(const float* p) {
    return *reinterpret_cast<const float4*>(p);
}
static __device__ __forceinline__ float dot4(float4 a, float4 b) {
    return a.x * b.x + a.y * b.y + a.z * b.z + a.w * b.w;
}
static __device__ __forceinline__ float4 f4add(float4 a, float4 b) {
    return make_float4(a.x + b.x, a.y + b.y, a.z + b.z, a.w + b.w);
}
static __device__ __forceinline__ float4 f4mul(float4 a, float4 b) {
    return make_float4(a.x * b.x, a.y * b.y, a.z * b.z, a.w * b.w);
}

// ---------------------------------------------------------------------------
// K1: per (n,h) row — L2-normalize x, write xn two layouts, conv+softmax.
// ---------------------------------------------------------------------------
__global__ __launch_bounds__(256) void k1_norm_softmax(
    const float* __restrict__ x, const float* __restrict__ conv_w,
    float* __restrict__ xnT, float* __restrict__ xnP, float* __restrict__ sa)
{
    __shared__ float xrow[C_ * W_];       // [c][w]
    __shared__ float conv_s[K_ * CVP_];   // [k][132]
    __shared__ float xrowT[W_ * CVP_];    // [w][132]
    __shared__ float invn[W_];
    __shared__ float s_s[K_ * W_];        // [k][w]

    const int b = blockIdx.x;             // n*H + h
    const int n = b / H_, h = b - n * H_;
    const int t = threadIdx.x;

    for (int i = t; i < C_ * W_; i += 256) {
        const int c = i / W_, w = i - c * W_;
        xrow[i] = x[(size_t)(n * C_ + c) * HW_ + h * W_ + w];
    }
    for (int i = t; i < K_ * C_; i += 256) {
        const int k = i >> 7, c = i & 127;
        conv_s[k * CVP_ + c] = conv_w[i];
    }
    __syncthreads();

    if (t < W_) {
        float s = 0.f;
        for (int c = 0; c < C_; ++c) { const float v = xrow[c * W_ + t]; s += v * v; }
        invn[t] = 1.f / fmaxf(sqrtf(s), EPSV);
    }
    __syncthreads();

    for (int i = t; i < C_ * W_; i += 256) {
        const int c = i / W_, w = i - c * W_;
        const float v = xrow[i] * invn[w];
        xrow[i] = v;
        xnT[(size_t)(n * C_ + c) * HW_ + h * W_ + w] = v;
    }
    __syncthreads();

    for (int i = t; i < W_ * C_; i += 256) {
        const int w = i / C_, c = i - w * C_;
        const float v = xrow[c * W_ + w];
        xnP[((size_t)n * HW_ + h * W_ + w) * C_ + c] = v;
        xrowT[w * CVP_ + c] = v;
    }
    __syncthreads();

    {
        const int k = t >> 2, q = t & 3;
        float acc0 = 0.f, acc1 = 0.f, acc2 = 0.f, acc3 = 0.f, acc4 = 0.f;
        float acc5 = 0.f, acc6 = 0.f, acc7 = 0.f, acc8 = 0.f, acc9 = 0.f;
        const float* convk = &conv_s[k * CVP_];
        for (int ch = 0; ch < 4; ++ch) {
            float4 cv0 = ld4(convk + ch * 32 + 0),  cv1 = ld4(convk + ch * 32 + 4);
            float4 cv2 = ld4(convk + ch * 32 + 8),  cv3 = ld4(convk + ch * 32 + 12);
            float4 cv4 = ld4(convk + ch * 32 + 16), cv5 = ld4(convk + ch * 32 + 20);
            float4 cv6 = ld4(convk + ch * 32 + 24), cv7 = ld4(convk + ch * 32 + 28);
#pragma unroll
            for (int wi = 0; wi < 10; ++wi) {
                const float* xw = &xrowT[(q * 10 + wi) * CVP_ + ch * 32];
                float s = dot4(cv0, ld4(xw)) + dot4(cv1, ld4(xw + 4))
                        + dot4(cv2, ld4(xw + 8)) + dot4(cv3, ld4(xw + 12))
                        + dot4(cv4, ld4(xw + 16)) + dot4(cv5, ld4(xw + 20))
                        + dot4(cv6, ld4(xw + 24)) + dot4(cv7, ld4(xw + 28));
                if      (wi == 0) acc0 += s; else if (wi == 1) acc1 += s;
                else if (wi == 2) acc2 += s; else if (wi == 3) acc3 += s;
                else if (wi == 4) acc4 += s; else if (wi == 5) acc5 += s;
                else if (wi == 6) acc6 += s; else if (wi == 7) acc7 += s;
                else if (wi == 8) acc8 += s; else              acc9 += s;
            }
        }
        float* sd = &s_s[k * W_ + q * 10];
        sd[0] = acc0; sd[1] = acc1; sd[2] = acc2; sd[3] = acc3; sd[4] = acc4;
        sd[5] = acc5; sd[6] = acc6; sd[7] = acc7; sd[8] = acc8; sd[9] = acc9;
    }
    __syncthreads();

    if (t < W_) {
        const int w = t;
        float m = -1e30f;
        for (int k = 0; k < K_; ++k) m = fmaxf(m, s_s[k * W_ + w]);
        float sum = 0.f;
        for (int k = 0; k < K_; ++k) sum += expf(s_s[k * W_ + w] - m);
        const float inv = 1.f / sum;
        for (int k = 0; k < K_; ++k)
            sa[(size_t)(n * K_ + k) * HW_ + h * W_ + w] = expf(s_s[k * W_ + w] - m) * inv;
    }
}

// ---------------------------------------------------------------------------
// Strip colsum: thread t<140 owns (channel-quad q2 = t/70, strip = t%70).
// A strip = 4 output rows (h0..h0+nh-1) × one w-float4 for 4 channels
// {cA, cA+4, cA+8, cA+12}. Loads 7 rows once (28 dwordx4) → 16 pixel-outputs
// (7 loads/slot vs 16 for the old per-slot scheme).
// ---------------------------------------------------------------------------
#define COLSUM_STRIP(cs_q, sa_s, xb, cA_base)                                   \
    if (t < 140) {                                                              \
        const int q2 = t / 70, item = t - q2 * 70;                              \
        const int hq = item / 10, wq = item - hq * 10;                          \
        const int h0 = 4 * hq;                                                  \
        const int nh = (hq < 6) ? 4 : 3;                                        \
        const int cA = (cA_base) + q2 * 16;                                     \
        const float* xp0 = xb + (size_t)(cA + 0)  * HW_ + h0 * W_ + 4 * wq;     \
        const float* xp1 = xb + (size_t)(cA + 4)  * HW_ + h0 * W_ + 4 * wq;     \
        const float* xp2 = xb + (size_t)(cA + 8)  * HW_ + h0 * W_ + 4 * wq;     \
        const float* xp3 = xb + (size_t)(cA + 12) * HW_ + h0 * W_ + 4 * wq;     \
        const float* sap = &sa_s[h0 * W_ + 4 * wq];                             \
        float4 p0[7], p1[7], p2[7], p3[7];                                      \
        _Pragma("unroll")                                                       \
        for (int r = 0; r < 7; ++r) {                                           \
            const float4 sv = ld4(sap + r * W_);                                \
            p0[r] = f4mul(sv, ld4(xp0 + r * W_));                               \
            p1[r] = f4mul(sv, ld4(xp1 + r * W_));                               \
            p2[r] = f4mul(sv, ld4(xp2 + r * W_));                               \
            p3[r] = f4mul(sv, ld4(xp3 + r * W_));                               \
        }                                                                       \
        _Pragma("unroll")                                                       \
        for (int hh = 0; hh < 4; ++hh) {                                        \
            if (hh < nh) {                                                      \
                const float4 c0v = f4add(f4add(p0[hh], p0[hh+1]), f4add(p0[hh+2], p0[hh+3])); \
                const float4 c1v = f4add(f4add(p1[hh], p1[hh+1]), f4add(p1[hh+2], p1[hh+3])); \
                const float4 c2v = f4add(f4add(p2[hh], p2[hh+1]), f4add(p2[hh+2], p2[hh+3])); \
                const float4 c3v = f4add(f4add(p3[hh], p3[hh+1]), f4add(p3[hh+2], p3[hh+3])); \
                const int s = 10 * (h0 + hh) + wq;                              \
                cs_q[q2][0][s] = make_float4(c0v.x, c1v.x, c2v.x, c3v.x);       \
                cs_q[q2][1][s] = make_float4(c0v.y, c1v.y, c2v.y, c3v.y);       \
                cs_q[q2][2][s] = make_float4(c0v.z, c1v.z, c2v.z, c3v.z);       \
                cs_q[q2][3][s] = make_float4(c0v.w, c1v.w, c2v.w, c3v.w);       \
            }                                                                   \
        }                                                                       \
    }

// 10-value window read over one quad array csq[4][SL_+1].
#define WINDOW10(csq, b0, d, A0, A1, A2, A3)                                    \
    {                                                                           \
        float4 v0 = csq[(b0 + 0) & 3][(b0 + 0) >> 2];                           \
        float4 v1 = csq[(b0 + 1) & 3][(b0 + 1) >> 2];                           \
        float4 v2 = csq[(b0 + 2) & 3][(b0 + 2) >> 2];                           \
        float4 v3 = csq[(b0 + 3) & 3][(b0 + 3) >> 2];                           \
        float4 v4 = csq[(b0 + 4) & 3][(b0 + 4) >> 2];                           \
        float4 v5 = csq[(b0 + 5) & 3][(b0 + 5) >> 2];                           \
        float4 v6 = csq[(b0 + 6) & 3][(b0 + 6) >> 2];                           \
        float4 v7 = csq[(b0 + 7) & 3][(b0 + 7) >> 2];                           \
        float4 v8 = csq[(b0 + 8) & 3][(b0 + 8) >> 2];                           \
        float4 v9 = csq[(b0 + 9) & 3][(b0 + 9) >> 2];                           \
        const float4 t0 = f4add(v0, v1), t1 = f4add(v1, v2), t2 = f4add(v2, v3);\
        const float4 t3 = f4add(v3, v4), t4 = f4add(v4, v5), t5 = f4add(v5, v6);\
        const float4 t6 = f4add(v6, v7), t7 = f4add(v7, v8), t8 = f4add(v8, v9);\
        const float4 w0 = f4add(t0, t2), w1 = f4add(t1, t3), w2 = f4add(t2, t4);\
        const float4 w3 = f4add(t3, t5), w4 = f4add(t4, t6), w5 = f4add(t5, t7);\
        const float4 w6 = f4add(t6, t8);                                        \
        A0 = (0 < d) ? w0 : w3;                                                 \
        A1 = (1 < d) ? w1 : w4;                                                 \
        A2 = (2 < d) ? w2 : w5;                                                 \
        A3 = (3 < d) ? w3 : w6;                                                 \
    }

// ---------------------------------------------------------------------------
// K4m: merged launch. blocks[0,256): vlad_global; blocks[256,1280): norm pass
//      (strip colsum, 8 channels/iteration, 4 iterations).
// ---------------------------------------------------------------------------
__global__ __launch_bounds__(256) void k4_merged(
    const float* __restrict__ sa, const float* __restrict__ xnT,
    const float* __restrict__ xnP, const float* __restrict__ cent,
    float* __restrict__ nsqp, float* __restrict__ vg_u,
    float* __restrict__ vg_r)
{
    __shared__ float  sa_s[1248];         // 31 rows + pad (strip r=6 / window overreads)
    __shared__ float4 cs_q[2][4][SL_ + 1];
    __shared__ float  gs[256], bss[256];
    __shared__ float  red[2];

    const int t = threadIdx.x;

    if (blockIdx.x < 256) {
        const int b = blockIdx.x;         // n*K + k
        const int n = b >> 6, k = b & 63;
        const int c = t & 127, half = t >> 7;
        constexpr int HHW = HW_ / 2;      // 600

        const float* sarow = &sa[(size_t)b * HW_ + half * HHW];
        const float* xp = &xnP[((size_t)n * HW_ + half * HHW) * C_ + c];
        float g0 = 0.f, g1 = 0.f, g2 = 0.f, g3 = 0.f;
        float b0 = 0.f, b1 = 0.f, b2 = 0.f, b3 = 0.f;
        for (int pix = 0; pix < HHW; pix += 4) {
            const float s0 = sarow[pix + 0], s1 = sarow[pix + 1];
            const float s2 = sarow[pix + 2], s3 = sarow[pix + 3];
            g0 += s0 * xp[(size_t)(pix + 0) * C_];
            g1 += s1 * xp[(size_t)(pix + 1) * C_];
            g2 += s2 * xp[(size_t)(pix + 2) * C_];
            g3 += s3 * xp[(size_t)(pix + 3) * C_];
            b0 += s0; b1 += s1; b2 += s2; b3 += s3;
        }
        gs[t]  = (g0 + g1) + (g2 + g3);
        bss[t] = (b0 + b1) + (b2 + b3);
        __syncthreads();

        float vg = 0.f;
        if (t < 128) {
            vg = (gs[t] + gs[t + 128]) - cent[k * C_ + c] * (bss[t] + bss[t + 128]);
            float nsq = vg * vg;
            for (int off = 32; off >= 1; off >>= 1) nsq += __shfl_down(nsq, off);
            if ((t & 63) == 0) red[t >> 6] = nsq;
        }
        __syncthreads();
        const float tot  = red[0] + red[1];
        const float norm = sqrtf(tot);
        const float iv   = 1.f / fmaxf(norm, EPSV);
        if (t < 128) vg_u[(size_t)b * C_ + t] = vg * iv;
        if (t == 0) { const float rr = norm * iv; vg_r[b] = rr * rr; }
        return;
    }

    const int b  = blockIdx.x - 256;      // ((n*K + k)*4 + cq)
    const int cq = b & 3;
    const int nk = b >> 2;
    const int n  = nk >> 6, k = nk & 63;

    for (int i = t; i < HW_; i += 256) sa_s[i] = sa[(size_t)nk * HW_ + i];
    __syncthreads();

    // sa box-sum windows (B) in registers (thread t<250 owns p0 = 4t..4t+3)
    int b0 = 0, d = 4;
    float Bw0 = 0.f, Bw1 = 0.f, Bw2 = 0.f, Bw3 = 0.f;
    if (t < 250) {
        const int p0 = 4 * t;
        const int hp0 = p0 / WP_;
        const int wp0 = p0 - hp0 * WP_;
        b0 = p0 + 3 * hp0;
        d  = WP_ - wp0;
        const float* r0 = &sa_s[hp0 * W_ + wp0];
        float sc[10];
#pragma unroll
        for (int j = 0; j < 10; ++j)
            sc[j] = r0[j] + r0[j + W_] + r0[j + 2 * W_] + r0[j + 3 * W_];
        const float u0 = sc[0] + sc[1], u1 = sc[1] + sc[2], u2 = sc[2] + sc[3];
        const float u3 = sc[3] + sc[4], u4 = sc[4] + sc[5], u5 = sc[5] + sc[6];
        const float u6 = sc[6] + sc[7], u7 = sc[7] + sc[8], u8 = sc[8] + sc[9];
        const float wB0 = u0 + u2, wB1 = u1 + u3, wB2 = u2 + u4;
        const float wB3 = u3 + u5, wB4 = u4 + u6, wB5 = u5 + u7, wB6 = u6 + u8;
        Bw0 = (0 < d) ? wB0 : wB3;
        Bw1 = (1 < d) ? wB1 : wB4;
        Bw2 = (2 < d) ? wB2 : wB5;
        Bw3 = (3 < d) ? wB3 : wB6;
    }

    float nsq0 = 0.f, nsq1 = 0.f, nsq2 = 0.f, nsq3 = 0.f;
    const float* xb = xnT + (size_t)n * C_ * HW_;

    for (int iter = 0; iter < 4; ++iter) {
        const int c0 = cq * 32 + iter;    // 8 channels: c0 + 4j, j=0..7
        __syncthreads();                  // prior iteration's cs_q readers done
        COLSUM_STRIP(cs_q, sa_s, xb, c0)
        __syncthreads();
        if (t < 250) {
            const float* ck = &cent[k * C_ + c0];
            const float4 ceA = make_float4(ck[0], ck[4], ck[8], ck[12]);
            const float4 ceB = make_float4(ck[16], ck[20], ck[24], ck[28]);
            float4 A0, A1, A2, A3, Q0, Q1, Q2, Q3;
            WINDOW10(cs_q[0], b0, d, A0, A1, A2, A3)
            WINDOW10(cs_q[1], b0, d, Q0, Q1, Q2, Q3)
            {
                const float4 e = make_float4(A0.x - ceA.x * Bw0, A0.y - ceA.y * Bw0,
                                             A0.z - ceA.z * Bw0, A0.w - ceA.w * Bw0);
                const float4 f = make_float4(Q0.x - ceB.x * Bw0, Q0.y - ceB.y * Bw0,
                                             Q0.z - ceB.z * Bw0, Q0.w - ceB.w * Bw0);
                nsq0 += dot4(e, e) + dot4(f, f);
            }
            {
                const float4 e = make_float4(A1.x - ceA.x * Bw1, A1.y - ceA.y * Bw1,
                                             A1.z - ceA.z * Bw1, A1.w - ceA.w * Bw1);
                const float4 f = make_float4(Q1.x - ceB.x * Bw1, Q1.y - ceB.y * Bw1,
                                             Q1.z - ceB.z * Bw1, Q1.w - ceB.w * Bw1);
                nsq1 += dot4(e, e) + dot4(f, f);
            }
            {
                const float4 e = make_float4(A2.x - ceA.x * Bw2, A2.y - ceA.y * Bw2,
                                             A2.z - ceA.z * Bw2, A2.w - ceA.w * Bw2);
                const float4 f = make_float4(Q2.x - ceB.x * Bw2, Q2.y - ceB.y * Bw2,
                                             Q2.z - ceB.z * Bw2, Q2.w - ceB.w * Bw2);
                nsq2 += dot4(e, e) + dot4(f, f);
            }
            {
                const float4 e = make_float4(A3.x - ceA.x * Bw3, A3.y - ceA.y * Bw3,
                                             A3.z - ceA.z * Bw3, A3.w - ceA.w * Bw3);
                const float4 f = make_float4(Q3.x - ceB.x * Bw3, Q3.y - ceB.y * Bw3,
                                             Q3.z - ceB.z * Bw3, Q3.w - ceB.w * Bw3);
                nsq3 += dot4(e, e) + dot4(f, f);
            }
        }
    }
    if (t < 250) {
        *reinterpret_cast<float4*>(&nsqp[(size_t)b * PS_ + 4 * t]) =
            make_float4(nsq0 * 0.00390625f, nsq1 * 0.00390625f,
                        nsq2 * 0.00390625f, nsq3 * 0.00390625f);
    }
}

// ---------------------------------------------------------------------------
// K5m: blocks[0,256): combine cq partials (float4 quads); [256,260): vg fin.
// ---------------------------------------------------------------------------
__global__ __launch_bounds__(256) void k5_merged(
    const float* __restrict__ nsqp, float* __restrict__ inv1,
    float* __restrict__ rloc, const float* __restrict__ vg_u,
    const float* __restrict__ vg_r, float* __restrict__ out)
{
    const int t = threadIdx.x;
    if (blockIdx.x >= 256) {
        const int n = blockIdx.x - 256;
        __shared__ float inv2s;
        if (t == 0) {
            float s = 0.f;
            for (int k = 0; k < K_; ++k) s += vg_r[n * K_ + k];
            inv2s = 1.f / fmaxf(sqrtf(s), EPSV);
        }
        __syncthreads();
        const float inv2 = inv2s;
        for (int i = t; i < KC_; i += 256)
            out[(size_t)n * KC_ + i] = vg_u[(size_t)n * KC_ + i] * inv2;
        return;
    }
    const int nk = blockIdx.x;
    if (t < 250) {
        const int p0 = 4 * t;
        const float4 a = ld4(&nsqp[(size_t)(nk * 4 + 0) * PS_ + p0]);
        const float4 b = ld4(&nsqp[(size_t)(nk * 4 + 1) * PS_ + p0]);
        const float4 c = ld4(&nsqp[(size_t)(nk * 4 + 2) * PS_ + p0]);
        const float4 e = ld4(&nsqp[(size_t)(nk * 4 + 3) * PS_ + p0]);
        float4 iv, rr;
#pragma unroll
        for (int j = 0; j < 4; ++j) {
            const float s = reinterpret_cast<const float*>(&a)[j]
                          + reinterpret_cast<const float*>(&b)[j]
                          + reinterpret_cast<const float*>(&c)[j]
                          + reinterpret_cast<const float*>(&e)[j];
            const float norm = sqrtf(s);
            const float v = 1.f / fmaxf(norm, EPSV);
            reinterpret_cast<float*>(&iv)[j] = v * 0.0625f;   // fold 1/16
            const float r = norm * v;
            reinterpret_cast<float*>(&rr)[j] = r * r;
        }
        *reinterpret_cast<float4*>(&inv1[(size_t)nk * PS_ + p0]) = iv;
        *reinterpret_cast<float4*>(&rloc[(size_t)nk * PS_ + p0]) = rr;
    }
}

// K6: inv2[n,p] = 1/max(sqrt(sum_k rloc),EPS) — float4 quads.
__global__ __launch_bounds__(256) void k6_inv2(
    const float* __restrict__ rloc, float* __restrict__ inv2)
{
    const int n = blockIdx.x;
    const int t = threadIdx.x;
    if (t < 250) {
        const int p0 = 4 * t;
        float4 s = make_float4(0, 0, 0, 0);
        for (int k = 0; k < K_; ++k) {
            const float4 r = ld4(&rloc[(size_t)(n * K_ + k) * PS_ + p0]);
            s = f4add(s, r);
        }
        float4 o;
        o.x = 1.f / fmaxf(sqrtf(s.x), EPSV);
        o.y = 1.f / fmaxf(sqrtf(s.y), EPSV);
        o.z = 1.f / fmaxf(sqrtf(s.z), EPSV);
        o.w = 1.f / fmaxf(sqrtf(s.w), EPSV);
        *reinterpret_cast<float4*>(&inv2[n * PS_ + p0]) = o;
    }
}

// ---------------------------------------------------------------------------
// K7w: WRITE pass — strip colsum (8 ch/iter), 10-read windows, aligned
//      float4 stores (m = iter, channels all ≡ m mod 4).
// ---------------------------------------------------------------------------
__global__ __launch_bounds__(256) void k7_write(
    const float* __restrict__ sa, const float* __restrict__ xnT,
    const float* __restrict__ cent, const float* __restrict__ inv1,
    const float* __restrict__ inv2, float* __restrict__ outl)
{
    __shared__ float  sa_s[1248];
    __shared__ float  scl_s[P_];
    __shared__ float  t2_s[P_];
    __shared__ float4 cs_q[2][4][SL_ + 1];

    const int b  = blockIdx.x;            // ((n*K + k)*4 + cq)
    const int cq = b & 3;
    const int nk = b >> 2;
    const int n  = nk >> 6, k = nk & 63;
    const int t  = threadIdx.x;

    for (int i = t; i < HW_; i += 256) sa_s[i] = sa[(size_t)nk * HW_ + i];
    __syncthreads();
    for (int p = t; p < P_; p += 256) {
        const int hp = p / WP_, wp = p - hp * WP_;
        float bs = 0.f;
#pragma unroll
        for (int dh = 0; dh < 4; ++dh) {
            const float* r = &sa_s[(hp + dh) * W_ + wp];
            bs += r[0] + r[1] + r[2] + r[3];
        }
        const float sc = inv1[(size_t)nk * PS_ + p] * inv2[n * PS_ + p];
        scl_s[p] = sc;
        t2_s[p]  = bs * sc;
    }

    const float* xb = xnT + (size_t)n * C_ * HW_;
    float* ob = outl + (size_t)nk * CP_;

    for (int iter = 0; iter < 4; ++iter) {
        const int m = iter;
        const int c0 = cq * 32 + m;       // 8 channels: c0 + 4j, all ≡ m mod 4
        __syncthreads();                  // prior iteration's cs_q readers done
        COLSUM_STRIP(cs_q, sa_s, xb, c0)
        __syncthreads();
        const float* ck = &cent[k * C_ + c0];
        const float ce0 = ck[0],  ce1 = ck[4],  ce2 = ck[8],  ce3 = ck[12];
        const float ce4 = ck[16], ce5 = ck[20], ce6 = ck[24], ce7 = ck[28];
        float* ob0 = ob + (size_t)(c0 + 0)  * P_;
        float* ob1 = ob + (size_t)(c0 + 4)  * P_;
        float* ob2 = ob + (size_t)(c0 + 8)  * P_;
        float* ob3 = ob + (size_t)(c0 + 12) * P_;
        float* ob4 = ob + (size_t)(c0 + 16) * P_;
        float* ob5 = ob + (size_t)(c0 + 20) * P_;
        float* ob6 = ob + (size_t)(c0 + 24) * P_;
        float* ob7 = ob + (size_t)(c0 + 28) * P_;

        if (t < 249) {                                 // vector: p ∈ [m, m+996)
            const int p0 = m + 4 * t;
            const int hp0 = p0 / WP_;
            const int wp0 = p0 - hp0 * WP_;
            const int b0 = p0 + 3 * hp0;
            const int d  = WP_ - wp0;
            const float sc0 = scl_s[p0 + 0], sc1 = scl_s[p0 + 1];
            const float sc2 = scl_s[p0 + 2], sc3 = scl_s[p0 + 3];
            const float tt0 = t2_s[p0 + 0], tt1 = t2_s[p0 + 1];
            const float tt2 = t2_s[p0 + 2], tt3 = t2_s[p0 + 3];
            float4 A0, A1, A2, A3, Q0, Q1, Q2, Q3;
            WINDOW10(cs_q[0], b0, d, A0, A1, A2, A3)
            WINDOW10(cs_q[1], b0, d, Q0, Q1, Q2, Q3)
            *reinterpret_cast<float4*>(ob0 + p0) =
                make_float4(A0.x * sc0 - ce0 * tt0, A1.x * sc1 - ce0 * tt1,
                            A2.x * sc2 - ce0 * tt2, A3.x * sc3 - ce0 * tt3);
            *reinterpret_cast<float4*>(ob1 + p0) =
                make_float4(A0.y * sc0 - ce1 * tt0, A1.y * sc1 - ce1 * tt1,
                            A2.y * sc2 - ce1 * tt2, A3.y * sc3 - ce1 * tt3);
            *reinterpret_cast<float4*>(ob2 + p0) =
                make_float4(A0.z * sc0 - ce2 * tt0, A1.z * sc1 - ce2 * tt1,
                            A2.z * sc2 - ce2 * tt2, A3.z * sc3 - ce2 * tt3);
            *reinterpret_cast<float4*>(ob3 + p0) =
                make_float4(A0.w * sc0 - ce3 * tt0, A1.w * sc1 - ce3 * tt1,
                            A2.w * sc2 - ce3 * tt2, A3.w * sc3 - ce3 * tt3);
            *reinterpret_cast<float4*>(ob4 + p0) =
                make_float4(Q0.x * sc0 - ce4 * tt0, Q1.x * sc1 - ce4 * tt1,
                            Q2.x * sc2 - ce4 * tt2, Q3.x * sc3 - ce4 * tt3);
            *reinterpret_cast<float4*>(ob5 + p0) =
                make_float4(Q0.y * sc0 - ce5 * tt0, Q1.y * sc1 - ce5 * tt1,
                            Q2.y * sc2 - ce5 * tt2, Q3.y * sc3 - ce5 * tt3);
            *reinterpret_cast<float4*>(ob6 + p0) =
                make_float4(Q0.z * sc0 - ce6 * tt0, Q1.z * sc1 - ce6 * tt1,
                            Q2.z * sc2 - ce6 * tt2, Q3.z * sc3 - ce6 * tt3);
            *reinterpret_cast<float4*>(ob7 + p0) =
                make_float4(Q0.w * sc0 - ce7 * tt0, Q1.w * sc1 - ce7 * tt1,
                            Q2.w * sc2 - ce7 * tt2, Q3.w * sc3 - ce7 * tt3);
        } else if (t < 252) {                          // 3 scalar stragglers
            const int u = t - 249;
            const int p = (u < m) ? u : 996 + u;       // {0..m-1} ∪ {m+996..998}
            const int hp = p / WP_, wp = p - hp * WP_;
            const int base = hp * W_ + wp;
            const float4 a0 = cs_q[0][(base + 0) & 3][(base + 0) >> 2];
            const float4 a1 = cs_q[0][(base + 1) & 3][(base + 1) >> 2];
            const float4 a2 = cs_q[0][(base + 2) & 3][(base + 2) >> 2];
            const float4 a3 = cs_q[0][(base + 3) & 3][(base + 3) >> 2];
            const float4 q0 = cs_q[1][(base + 0) & 3][(base + 0) >> 2];
            const float4 q1 = cs_q[1][(base + 1) & 3][(base + 1) >> 2];
            const float4 q2 = cs_q[1][(base + 2) & 3][(base + 2) >> 2];
            const float4 q3 = cs_q[1][(base + 3) & 3][(base + 3) >> 2];
            const float sc = scl_s[p], tt = t2_s[p];
            ob0[p] = (a0.x + a1.x + a2.x + a3.x) * sc - ce0 * tt;
            ob1[p] = (a0.y + a1.y + a2.y + a3.y) * sc - ce1 * tt;
            ob2[p] = (a0.z + a1.z + a2.z + a3.z) * sc - ce2 * tt;
            ob3[p] = (a0.w + a1.w + a2.w + a3.w) * sc - ce3 * tt;
            ob4[p] = (q0.x + q1.x + q2.x + q3.x) * sc - ce4 * tt;
            ob5[p] = (q0.y + q1.y + q2.y + q3.y) * sc - ce5 * tt;
            ob6[p] = (q0.z + q1.z + q2.z + q3.z) * sc - ce6 * tt;
            ob7[p] = (q0.w + q1.w + q2.w + q3.w) * sc - ce7 * tt;
        }
    }
}

// ---------------------------------------------------------------------------
extern "C" void kernel_launch(void* const* d_in, const int* in_sizes, int n_in,
                              void* d_out, int out_size, void* d_ws, size_t ws_size,
                              hipStream_t stream)
{
    const float* x      = (const float*)d_in[0];
    const float* conv_w = (const float*)d_in[1];
    const float* cent   = (const float*)d_in[2];
    float* out = (float*)d_out;
    float* ws  = (float*)d_ws;

    // workspace layout (floats); p-indexed buffers use padded stride 1000
    float* xnT  = ws;                       // 614400
    float* xnP  = ws + 614400;              // 614400
    float* sa   = ws + 1228800;             // 307200
    float* vg_u = ws + 1536000;             // 32768
    float* vg_r = ws + 1568768;             // 256
    float* nsqp = ws + 1569024;             // 1024*1000 = 1024000
    float* inv1 = ws + 2593024;             // 256*1000  = 256000
    float* rloc = ws + 2849024;             // 256*1000  = 256000
    float* inv2 = ws + 3105024;             // 4*1000    = 4000

    float* outl = out + (size_t)N_ * KC_;   // output 1 region

    k1_norm_softmax<<<N_ * H_, 256, 0, stream>>>(x, conv_w, xnT, xnP, sa);
    k4_merged<<<256 + N_ * K_ * 4, 256, 0, stream>>>(sa, xnT, xnP, cent,
                                                     nsqp, vg_u, vg_r);
    k5_merged<<<256 + N_, 256, 0, stream>>>(nsqp, inv1, rloc, vg_u, vg_r, out);
    k6_inv2<<<N_, 256, 0, stream>>>(rloc, inv2);
    k7_write<<<N_ * K_ * 4, 256, 0, stream>>>(sa, xnT, cent, inv1, inv2, outl);
}